// Round 1
// baseline (977.703 us; speedup 1.0000x reference)
//
#include <hip/hip_runtime.h>
#include <stdint.h>

#define Bn 256
#define Nn 512
#define Fn 256
#define Hn 256
#define NSn 5
#define EPS 1e-5f

// ---------------------------------------------------------------------------
// K1: support = features @ W0.  M = B*N = 131072, K = F = 256, N = H = 256.
// BM=128 BN=128 BK=16, 256 threads, 8x8 microtile. Also zero-inits the argmax
// slots (block (0,0)) so the whole pipeline is one stream-ordered sequence.
// ---------------------------------------------------------------------------
__global__ __launch_bounds__(256) void k1_gemm(
    const float* __restrict__ A, const float* __restrict__ W,
    float* __restrict__ C, unsigned long long* __restrict__ slots)
{
  if (blockIdx.x == 0 && blockIdx.y == 0) {
    for (int i = (int)threadIdx.x; i < Bn * NSn; i += 256) slots[i] = 0ull;
  }
  __shared__ float As[16][128];   // transposed A tile: As[k][m]
  __shared__ float Bs[16][128];
  const int m0 = blockIdx.y * 128;
  const int n0 = blockIdx.x * 128;
  const int tid = (int)threadIdx.x;
  const int ty = tid >> 4;        // 0..15 -> rows ty*8..+8
  const int tx = tid & 15;        // 0..15 -> cols tx*8..+8
  float acc[8][8];
#pragma unroll
  for (int i = 0; i < 8; ++i)
#pragma unroll
    for (int j = 0; j < 8; ++j) acc[i][j] = 0.0f;

  for (int k0 = 0; k0 < Fn; k0 += 16) {
    // A tile 128x16: 512 float4, 2 per thread, store transposed
#pragma unroll
    for (int q = 0; q < 2; ++q) {
      int c = tid * 2 + q;                 // 0..511
      int row = c >> 2;
      int c4 = c & 3;
      float4 v = *(const float4*)(A + (size_t)(m0 + row) * Fn + k0 + c4 * 4);
      As[c4 * 4 + 0][row] = v.x;
      As[c4 * 4 + 1][row] = v.y;
      As[c4 * 4 + 2][row] = v.z;
      As[c4 * 4 + 3][row] = v.w;
    }
    // B tile 16x128: 512 float4, 2 per thread
#pragma unroll
    for (int q = 0; q < 2; ++q) {
      int c = tid * 2 + q;                 // 0..511
      int row = c >> 5;                    // 0..15
      int c4 = c & 31;
      *(float4*)(&Bs[row][c4 * 4]) =
          *(const float4*)(W + (size_t)(k0 + row) * Hn + n0 + c4 * 4);
    }
    __syncthreads();
#pragma unroll
    for (int kk = 0; kk < 16; ++kk) {
      float a[8], bb[8];
      *(float4*)(&a[0]) = *(const float4*)(&As[kk][ty * 8]);
      *(float4*)(&a[4]) = *(const float4*)(&As[kk][ty * 8 + 4]);
      *(float4*)(&bb[0]) = *(const float4*)(&Bs[kk][tx * 8]);
      *(float4*)(&bb[4]) = *(const float4*)(&Bs[kk][tx * 8 + 4]);
#pragma unroll
      for (int i = 0; i < 8; ++i)
#pragma unroll
        for (int j = 0; j < 8; ++j) acc[i][j] = fmaf(a[i], bb[j], acc[i][j]);
    }
    __syncthreads();
  }
#pragma unroll
  for (int i = 0; i < 8; ++i) {
    size_t r = (size_t)(m0 + ty * 8 + i) * Hn + n0 + tx * 8;
    *(float4*)(C + r)     = make_float4(acc[i][0], acc[i][1], acc[i][2], acc[i][3]);
    *(float4*)(C + r + 4) = make_float4(acc[i][4], acc[i][5], acc[i][6], acc[i][7]);
  }
}

// ---------------------------------------------------------------------------
// K2: per batch b: x = adj[b] @ support[b] + b0 ; LN0 ; ReLU ; per-row score ;
// per-(b,stage) argmax via encoded 64-bit atomicMax. x is NEVER stored.
// BM=64 (rows), BN=256 (full H -> LN is intra-block), BK=16, 256 thr, 8x8.
// Thread grid: ty=tid/32 (8 row groups of 8), tx=tid%32 (32 col groups of 8).
// Row reduction = 32-lane half-wave shuffle (ty groups align with half-waves).
// ---------------------------------------------------------------------------
__global__ __launch_bounds__(256) void k2_fused(
    const float* __restrict__ adj, const float* __restrict__ sup,
    const float* __restrict__ b0, const float* __restrict__ g0,
    const float* __restrict__ be0, const int* __restrict__ sid,
    unsigned long long* __restrict__ slots)
{
  __shared__ float As[16][64];    // transposed A tile
  __shared__ float Bs[16][256];
  const int b = blockIdx.y;
  const int m0 = blockIdx.x * 64;
  const int tid = (int)threadIdx.x;
  const int ty = tid >> 5;        // 0..7
  const int tx = tid & 31;        // 0..31
  const float* Ab = adj + (size_t)b * Nn * Nn;
  const float* Sb = sup + (size_t)b * Nn * Hn;
  float acc[8][8];
#pragma unroll
  for (int i = 0; i < 8; ++i)
#pragma unroll
    for (int j = 0; j < 8; ++j) acc[i][j] = 0.0f;

  for (int k0 = 0; k0 < Nn; k0 += 16) {
    {
      // A tile 64x16: 256 float4, 1 per thread, store transposed
      int row = tid >> 2;               // 0..63
      int c4 = tid & 3;
      float4 v = *(const float4*)(Ab + (size_t)(m0 + row) * Nn + k0 + c4 * 4);
      As[c4 * 4 + 0][row] = v.x;
      As[c4 * 4 + 1][row] = v.y;
      As[c4 * 4 + 2][row] = v.z;
      As[c4 * 4 + 3][row] = v.w;
    }
    // B tile 16x256: 1024 float4, 4 per thread
#pragma unroll
    for (int q = 0; q < 4; ++q) {
      int c = tid + 256 * q;            // 0..1023
      int row = c >> 6;                 // 0..15
      int c4 = c & 63;
      *(float4*)(&Bs[row][c4 * 4]) =
          *(const float4*)(Sb + (size_t)(k0 + row) * Hn + c4 * 4);
    }
    __syncthreads();
#pragma unroll
    for (int kk = 0; kk < 16; ++kk) {
      float a[8], bb[8];
      *(float4*)(&a[0]) = *(const float4*)(&As[kk][ty * 8]);
      *(float4*)(&a[4]) = *(const float4*)(&As[kk][ty * 8 + 4]);
      *(float4*)(&bb[0]) = *(const float4*)(&Bs[kk][tx * 8]);
      *(float4*)(&bb[4]) = *(const float4*)(&Bs[kk][tx * 8 + 4]);
#pragma unroll
      for (int i = 0; i < 8; ++i)
#pragma unroll
        for (int j = 0; j < 8; ++j) acc[i][j] = fmaf(a[i], bb[j], acc[i][j]);
    }
    __syncthreads();
  }

  // Epilogue: +b0, LN0, ReLU, score, argmax. Cols of this thread: tx*8..+8.
  float b0v[8], g0v[8], be0v[8];
#pragma unroll
  for (int j = 0; j < 8; ++j) {
    b0v[j] = b0[tx * 8 + j];
    g0v[j] = g0[tx * 8 + j];
    be0v[j] = be0[tx * 8 + j];
  }
#pragma unroll
  for (int i = 0; i < 8; ++i) {
    float s1 = 0.0f, s2 = 0.0f;
#pragma unroll
    for (int j = 0; j < 8; ++j) {
      float x = acc[i][j] + b0v[j];
      acc[i][j] = x;
      s1 += x;
      s2 += x * x;
    }
    // half-wave (32 lane) reduction — ty groups coincide with half-waves
#pragma unroll
    for (int off = 16; off >= 1; off >>= 1) {
      s1 += __shfl_xor(s1, off);
      s2 += __shfl_xor(s2, off);
    }
    float m = s1 * (1.0f / Hn);
    float var = s2 * (1.0f / Hn) - m * m;
    float rstd = 1.0f / sqrtf(var + EPS);
    float sc = 0.0f;
#pragma unroll
    for (int j = 0; j < 8; ++j) {
      float z = (acc[i][j] - m) * rstd * g0v[j] + be0v[j];
      sc += fmaxf(z, 0.0f);
    }
#pragma unroll
    for (int off = 16; off >= 1; off >>= 1) sc += __shfl_xor(sc, off);
    if (tx == 0) {
      int row = m0 + ty * 8 + i;
      int st = sid[b * Nn + row];
      // order-preserving float->uint map (handles any sign), low word encodes
      // ~row so that equal scores pick the SMALLEST row (jnp.argmax tie rule)
      unsigned int fb = __float_as_uint(sc);
      fb = (fb & 0x80000000u) ? ~fb : (fb | 0x80000000u);
      unsigned long long enc = ((unsigned long long)fb << 32) |
                               (unsigned long long)(0xFFFFFFFFu - (unsigned int)row);
      atomicMax(&slots[b * NSn + st], enc);
    }
  }
}

// ---------------------------------------------------------------------------
// Block-wide reductions (256 threads = 4 waves)
// ---------------------------------------------------------------------------
__device__ __forceinline__ float2 block_reduce_sum2(float a, float b) {
  __shared__ float r1[4], r2[4];
#pragma unroll
  for (int off = 32; off >= 1; off >>= 1) {
    a += __shfl_xor(a, off);
    b += __shfl_xor(b, off);
  }
  __syncthreads();   // protect r1/r2 from the previous call's readers
  if ((threadIdx.x & 63) == 0) {
    r1[threadIdx.x >> 6] = a;
    r2[threadIdx.x >> 6] = b;
  }
  __syncthreads();
  a = r1[0] + r1[1] + r1[2] + r1[3];
  b = r2[0] + r2[1] + r2[2] + r2[3];
  return make_float2(a, b);
}

__device__ __forceinline__ float block_reduce_sum(float a) {
  __shared__ float r1[4];
#pragma unroll
  for (int off = 32; off >= 1; off >>= 1) a += __shfl_xor(a, off);
  __syncthreads();
  if ((threadIdx.x & 63) == 0) r1[threadIdx.x >> 6] = a;
  __syncthreads();
  return r1[0] + r1[1] + r1[2] + r1[3];
}

// ---------------------------------------------------------------------------
// K3: one block per batch. Decode 5 winners, recompute their x-rows with one
// streamed pass over support[b] (5 accumulators/thread), then the whole tail:
// LN0+ReLU+b1 -> LN1+ReLU -> sum over stages -> @W2+b2 -> LN2+ReLU -> ·fcW+fcb
// ---------------------------------------------------------------------------
__global__ __launch_bounds__(256) void k3_final(
    const float* __restrict__ adj, const float* __restrict__ sup,
    const unsigned long long* __restrict__ slots,
    const float* __restrict__ b0, const float* __restrict__ b1,
    const float* __restrict__ W2, const float* __restrict__ b2,
    const float* __restrict__ g0, const float* __restrict__ be0,
    const float* __restrict__ g1, const float* __restrict__ be1,
    const float* __restrict__ g2, const float* __restrict__ be2,
    const float* __restrict__ fcW, const float* __restrict__ fcb,
    float* __restrict__ out)
{
  __shared__ float adjs[NSn][Nn];
  __shared__ float xs[Hn];
  const int b = blockIdx.x;
  const int tid = (int)threadIdx.x;

  int idxs[NSn];
#pragma unroll
  for (int s = 0; s < NSn; ++s) {
    unsigned long long e = slots[b * NSn + s];
    unsigned int id = 0xFFFFFFFFu - (unsigned int)(e & 0xFFFFFFFFull);
    if (id >= (unsigned int)Nn) id = 0;  // empty stage -> argmax(all -inf)=0
    idxs[s] = (int)id;
  }
#pragma unroll
  for (int s = 0; s < NSn; ++s) {
    const float* r = adj + ((size_t)b * Nn + idxs[s]) * Nn;
    for (int k = tid; k < Nn; k += 256) adjs[s][k] = r[k];
  }
  __syncthreads();

  // recompute x[b, idx_s, tid] for all 5 stages in one pass over support[b]
  float a0 = 0, a1 = 0, a2 = 0, a3 = 0, a4 = 0;
  const float* Sb = sup + (size_t)b * Nn * Hn;
#pragma unroll 8
  for (int k = 0; k < Nn; ++k) {
    float v = Sb[(size_t)k * Hn + tid];
    a0 = fmaf(adjs[0][k], v, a0);
    a1 = fmaf(adjs[1][k], v, a1);
    a2 = fmaf(adjs[2][k], v, a2);
    a3 = fmaf(adjs[3][k], v, a3);
    a4 = fmaf(adjs[4][k], v, a4);
  }
  float xr[NSn] = {a0, a1, a2, a3, a4};

  const float b0t = b0[tid], b1t = b1[tid];
  const float g0t = g0[tid], be0t = be0[tid];
  const float g1t = g1[tid], be1t = be1[tid];
  float xsum = 0.0f;
#pragma unroll
  for (int s = 0; s < NSn; ++s) {
    float x = xr[s] + b0t;
    float2 mv = block_reduce_sum2(x, x * x);
    float m = mv.x * (1.0f / Hn);
    float var = mv.y * (1.0f / Hn) - m * m;
    float z = (x - m) * (1.0f / sqrtf(var + EPS)) * g0t + be0t;
    float o = fmaxf(z, 0.0f) + b1t;                 // "out" row (pooled)
    float2 mv1 = block_reduce_sum2(o, o * o);
    float m1 = mv1.x * (1.0f / Hn);
    float v1 = mv1.y * (1.0f / Hn) - m1 * m1;
    float z1 = (o - m1) * (1.0f / sqrtf(v1 + EPS)) * g1t + be1t;
    xsum += fmaxf(z1, 0.0f);                        // Σ_s x1[b,s,:]
  }
  xs[tid] = xsum;
  __syncthreads();

  // y[tid] = Σ_h xs[h] * W2[h, tid] + b2[tid]
  float y = 0.0f;
#pragma unroll 8
  for (int h = 0; h < Hn; ++h) y = fmaf(xs[h], W2[(size_t)h * Hn + tid], y);
  y += b2[tid];
  float2 mv2 = block_reduce_sum2(y, y * y);
  float m2 = mv2.x * (1.0f / Hn);
  float v2 = mv2.y * (1.0f / Hn) - m2 * m2;
  float z2 = (y - m2) * (1.0f / sqrtf(v2 + EPS)) * g2[tid] + be2[tid];
  float p = fmaxf(z2, 0.0f) * fcW[tid];
  float tot = block_reduce_sum(p);
  if (tid == 0) out[b] = tot + fcb[0];
}

// ---------------------------------------------------------------------------
extern "C" void kernel_launch(void* const* d_in, const int* in_sizes, int n_in,
                              void* d_out, int out_size, void* d_ws, size_t ws_size,
                              hipStream_t stream)
{
  (void)in_sizes; (void)n_in; (void)out_size;
  const float* adj  = (const float*)d_in[0];
  const float* feat = (const float*)d_in[1];
  const int*   sid  = (const int*)d_in[2];
  const float* W0   = (const float*)d_in[3];
  const float* b0   = (const float*)d_in[4];
  const float* b1   = (const float*)d_in[5];
  const float* W2   = (const float*)d_in[6];
  const float* b2   = (const float*)d_in[7];
  const float* g0   = (const float*)d_in[8];
  const float* be0  = (const float*)d_in[9];
  const float* g1   = (const float*)d_in[10];
  const float* be1  = (const float*)d_in[11];
  const float* g2   = (const float*)d_in[12];
  const float* be2  = (const float*)d_in[13];
  const float* fcW  = (const float*)d_in[14];
  const float* fcb  = (const float*)d_in[15];
  float* out = (float*)d_out;

  // ws layout: support [B*N, H] fp32 (134,217,728 B) then 1280 argmax slots
  float* support = (float*)d_ws;
  unsigned long long* slots =
      (unsigned long long*)((char*)d_ws + (size_t)Bn * Nn * Hn * sizeof(float));
  (void)ws_size;  // requires ~134.3 MB

  dim3 grid1(Hn / 128, (Bn * Nn) / 128);   // (2, 1024)
  k1_gemm<<<grid1, dim3(256), 0, stream>>>(feat, W0, support, slots);

  dim3 grid2(Nn / 64, Bn);                 // (8, 256)
  k2_fused<<<grid2, dim3(256), 0, stream>>>(adj, support, b0, g0, be0, sid, slots);

  k3_final<<<dim3(Bn), dim3(256), 0, stream>>>(adj, support, slots,
      b0, b1, W2, b2, g0, be0, g1, be1, g2, be2, fcW, fcb, out);
}

// Round 2
// 866.815 us; speedup vs baseline: 1.1279x; 1.1279x over previous
//
#include <hip/hip_runtime.h>
#include <stdint.h>

#define Bn 256
#define Nn 512
#define Fn 256
#define Hn 256
#define NSn 5
#define EPS 1e-5f
#define LSTR 56   // LDS row stride in ushorts (112B: 16B-aligned, uniform bank spread)

typedef __attribute__((ext_vector_type(8))) short bf16x8;
typedef __attribute__((ext_vector_type(4))) float f32x4;

__device__ __forceinline__ unsigned short f2bf(float x) {
  unsigned int u = __float_as_uint(x);
  u += 0x7FFFu + ((u >> 16) & 1u);          // RTNE
  return (unsigned short)(u >> 16);
}
__device__ __forceinline__ unsigned int pack2bf(float a, float b) {
  return (unsigned int)f2bf(a) | ((unsigned int)f2bf(b) << 16);
}

// ---------------------------------------------------------------------------
// k0: W0T[h][f] = bf16(W0[f][h])  (B^T layout for k1's MFMA B fragments)
// ---------------------------------------------------------------------------
__global__ __launch_bounds__(256) void k0_prep(const float* __restrict__ W0,
                                               unsigned short* __restrict__ W0T) {
  int idx = blockIdx.x * 256 + (int)threadIdx.x;   // 65536
  int h = idx >> 8, f = idx & 255;
  W0T[h * Fn + f] = f2bf(W0[(size_t)f * Hn + h]);
}

// ---------------------------------------------------------------------------
// k1: supT[b][h][node] = bf16( (features @ W0)[node][h] )  via MFMA bf16.
// BM=64 rows, full 256 cols. 4 waves, each owns a 64-col strip (4x4 frag grid).
// ---------------------------------------------------------------------------
__global__ __launch_bounds__(256) void k1_support(
    const float* __restrict__ feat, const unsigned short* __restrict__ W0T,
    unsigned short* __restrict__ supT)
{
  __shared__ __align__(16) unsigned short As[64 * LSTR];
  __shared__ __align__(16) unsigned short Bs[256 * LSTR];
  const int tid = (int)threadIdx.x;
  const int wv = tid >> 6, lane = tid & 63;
  const int m0 = blockIdx.x * 64;
  f32x4 acc[4][4];
  const f32x4 z4 = {0.f, 0.f, 0.f, 0.f};
#pragma unroll
  for (int i = 0; i < 4; ++i)
#pragma unroll
    for (int j = 0; j < 4; ++j) acc[i][j] = z4;

  const int ar = tid >> 2, ac = tid & 3;
  for (int k0 = 0; k0 < Fn; k0 += 32) {
    // A tile 64x32 fp32 -> bf16 (rows = nodes, layout [m][k])
    const float* ap = feat + (size_t)(m0 + ar) * Fn + k0 + ac * 4;
    float4 v0 = *(const float4*)ap;
    float4 v1 = *(const float4*)(ap + 16);
    *(uint2*)&As[ar * LSTR + ac * 4] =
        make_uint2(pack2bf(v0.x, v0.y), pack2bf(v0.z, v0.w));
    *(uint2*)&As[ar * LSTR + 16 + ac * 4] =
        make_uint2(pack2bf(v1.x, v1.y), pack2bf(v1.z, v1.w));
    // B tile: W0T rows h=0..255, k-slice 32 (bf16 copy)
#pragma unroll
    for (int q = 0; q < 4; ++q) {
      int s = q * 256 + tid;
      int h = s >> 2, c = s & 3;
      *(uint4*)&Bs[h * LSTR + c * 8] =
          *(const uint4*)(W0T + (size_t)h * Fn + k0 + c * 8);
    }
    __syncthreads();
    bf16x8 af[4], bfr[4];
#pragma unroll
    for (int i = 0; i < 4; ++i) {
      af[i]  = *(const bf16x8*)&As[(i * 16 + (lane & 15)) * LSTR + (lane >> 4) * 8];
      bfr[i] = *(const bf16x8*)&Bs[(wv * 64 + i * 16 + (lane & 15)) * LSTR + (lane >> 4) * 8];
    }
#pragma unroll
    for (int mi = 0; mi < 4; ++mi)
#pragma unroll
      for (int nt = 0; nt < 4; ++nt)
        acc[mi][nt] = __builtin_amdgcn_mfma_f32_16x16x32_bf16(af[mi], bfr[nt], acc[mi][nt], 0, 0, 0);
    __syncthreads();
  }
  // epilogue: C row=(lane>>4)*4+reg (node), col=lane&15 (h) -> supT[b][h][node]
  const int b = m0 >> 9;
  const int nodebase = m0 & 511;
  unsigned short* outb = supT + ((size_t)b << 17);
#pragma unroll
  for (int mi = 0; mi < 4; ++mi)
#pragma unroll
    for (int nt = 0; nt < 4; ++nt) {
      int h = wv * 64 + nt * 16 + (lane & 15);
      int node = nodebase + mi * 16 + (lane >> 4) * 4;
      *(uint2*)(outb + (size_t)h * Nn + node) =
          make_uint2(pack2bf(acc[mi][nt][0], acc[mi][nt][1]),
                     pack2bf(acc[mi][nt][2], acc[mi][nt][3]));
    }
}

// ---------------------------------------------------------------------------
// k2: per batch, scores[node] = sum_h relu(LN0(adj@sup + b0)) via MFMA bf16.
// BM=64, full 256 cols; fused LN epilogue; x never stored.
// blockIdx: b = id & 255 (same-batch blocks share an XCD for supT L2 reuse).
// ---------------------------------------------------------------------------
__global__ __launch_bounds__(256) void k2_scores(
    const float* __restrict__ adj, const unsigned short* __restrict__ supT,
    const float* __restrict__ b0, const float* __restrict__ g0,
    const float* __restrict__ be0, float* __restrict__ scores)
{
  __shared__ __align__(16) unsigned short As[64 * LSTR];
  __shared__ __align__(16) unsigned short Bs[256 * LSTR];
  const int tid = (int)threadIdx.x;
  const int wv = tid >> 6, lane = tid & 63;
  const int b = blockIdx.x & 255;
  const int m0 = (blockIdx.x >> 8) * 64;
  const float* adjb = adj + ((size_t)b << 18);
  const unsigned short* supb = supT + ((size_t)b << 17);
  f32x4 acc[4][4];
  const f32x4 z4 = {0.f, 0.f, 0.f, 0.f};
#pragma unroll
  for (int i = 0; i < 4; ++i)
#pragma unroll
    for (int j = 0; j < 4; ++j) acc[i][j] = z4;

  const int ar = tid >> 2, ac = tid & 3;
  for (int k0 = 0; k0 < Nn; k0 += 32) {
    const float* ap = adjb + (size_t)(m0 + ar) * Nn + k0 + ac * 4;
    float4 v0 = *(const float4*)ap;
    float4 v1 = *(const float4*)(ap + 16);
    *(uint2*)&As[ar * LSTR + ac * 4] =
        make_uint2(pack2bf(v0.x, v0.y), pack2bf(v0.z, v0.w));
    *(uint2*)&As[ar * LSTR + 16 + ac * 4] =
        make_uint2(pack2bf(v1.x, v1.y), pack2bf(v1.z, v1.w));
#pragma unroll
    for (int q = 0; q < 4; ++q) {
      int s = q * 256 + tid;
      int h = s >> 2, c = s & 3;
      *(uint4*)&Bs[h * LSTR + c * 8] =
          *(const uint4*)(supb + (size_t)h * Nn + k0 + c * 8);
    }
    __syncthreads();
    bf16x8 af[4], bfr[4];
#pragma unroll
    for (int i = 0; i < 4; ++i) {
      af[i]  = *(const bf16x8*)&As[(i * 16 + (lane & 15)) * LSTR + (lane >> 4) * 8];
      bfr[i] = *(const bf16x8*)&Bs[(wv * 64 + i * 16 + (lane & 15)) * LSTR + (lane >> 4) * 8];
    }
#pragma unroll
    for (int mi = 0; mi < 4; ++mi)
#pragma unroll
      for (int nt = 0; nt < 4; ++nt)
        acc[mi][nt] = __builtin_amdgcn_mfma_f32_16x16x32_bf16(af[mi], bfr[nt], acc[mi][nt], 0, 0, 0);
    __syncthreads();
  }

  // Epilogue: LN0 + relu + row sum. red: [0..255]=s1[row][wv],[256..511]=s2,[512..767]=sc
  float* red = (float*)As;
  float b0v[4], g0v[4], be0v[4];
#pragma unroll
  for (int nt = 0; nt < 4; ++nt) {
    int col = wv * 64 + nt * 16 + (lane & 15);
    b0v[nt] = b0[col]; g0v[nt] = g0[col]; be0v[nt] = be0[col];
  }
#pragma unroll
  for (int mi = 0; mi < 4; ++mi)
#pragma unroll
    for (int rg = 0; rg < 4; ++rg) {
      float s1 = 0.f, s2 = 0.f;
#pragma unroll
      for (int nt = 0; nt < 4; ++nt) {
        float x = acc[mi][nt][rg] + b0v[nt];
        s1 += x; s2 += x * x;
      }
#pragma unroll
      for (int off = 8; off >= 1; off >>= 1) {
        s1 += __shfl_xor(s1, off);
        s2 += __shfl_xor(s2, off);
      }
      if ((lane & 15) == 0) {
        int row = mi * 16 + (lane >> 4) * 4 + rg;
        red[row * 4 + wv] = s1;
        red[256 + row * 4 + wv] = s2;
      }
    }
  __syncthreads();
#pragma unroll
  for (int mi = 0; mi < 4; ++mi)
#pragma unroll
    for (int rg = 0; rg < 4; ++rg) {
      int row = mi * 16 + (lane >> 4) * 4 + rg;
      float s1 = red[row*4] + red[row*4+1] + red[row*4+2] + red[row*4+3];
      float s2 = red[256+row*4] + red[256+row*4+1] + red[256+row*4+2] + red[256+row*4+3];
      float m = s1 * (1.0f / Hn);
      float var = s2 * (1.0f / Hn) - m * m;
      float rstd = 1.0f / sqrtf(var + EPS);
      float sc = 0.f;
#pragma unroll
      for (int nt = 0; nt < 4; ++nt) {
        float x = acc[mi][nt][rg] + b0v[nt];
        float zz = (x - m) * rstd * g0v[nt] + be0v[nt];
        sc += fmaxf(zz, 0.f);
      }
#pragma unroll
      for (int off = 8; off >= 1; off >>= 1) sc += __shfl_xor(sc, off);
      if ((lane & 15) == 0) red[512 + row * 4 + wv] = sc;
    }
  __syncthreads();
  if (tid < 64) {
    float s = red[512+tid*4] + red[512+tid*4+1] + red[512+tid*4+2] + red[512+tid*4+3];
    scores[b * Nn + m0 + tid] = s;
  }
}

// ---------------------------------------------------------------------------
__device__ __forceinline__ float brs(float v) {
  __shared__ float sb[4];
#pragma unroll
  for (int off = 32; off >= 1; off >>= 1) v += __shfl_xor(v, off);
  __syncthreads();
  if ((threadIdx.x & 63) == 0) sb[threadIdx.x >> 6] = v;
  __syncthreads();
  return sb[0] + sb[1] + sb[2] + sb[3];
}

// ---------------------------------------------------------------------------
// k3: one block/batch. Top-4 candidates per stage from bf16 scores; exact
// re-scoring via x = (adj_row@feat)@W0 with fp64 accumulation; then the whole
// tail (LN0,+b1,LN1,sum_s,@W2+b2,LN2,fc) in fp32.
// ---------------------------------------------------------------------------
__global__ __launch_bounds__(256) void k3_final(
    const float* __restrict__ adj, const float* __restrict__ feat,
    const float* __restrict__ scores, const int* __restrict__ sid,
    const float* __restrict__ W0, const float* __restrict__ b0,
    const float* __restrict__ b1, const float* __restrict__ W2,
    const float* __restrict__ b2, const float* __restrict__ g0,
    const float* __restrict__ be0, const float* __restrict__ g1,
    const float* __restrict__ be1, const float* __restrict__ g2,
    const float* __restrict__ be2, const float* __restrict__ fcW,
    const float* __restrict__ fcb, float* __restrict__ out)
{
  __shared__ float sc_s[Nn];
  __shared__ int sid_s[Nn];
  __shared__ __align__(16) float tT[Fn][20];   // t transposed, fp32
  __shared__ float xb[20][Hn];
  __shared__ unsigned long long redk[4];
  __shared__ int cand[20];
  __shared__ int candv[20];
  __shared__ float cm[20], cr[20], csc[20];
  __shared__ float xs[Hn];
  __shared__ int winslot[NSn];
  const int tid = (int)threadIdx.x;
  const int b = blockIdx.x;

  for (int i = tid; i < Nn; i += 256) {
    sc_s[i] = scores[b * Nn + i];
    sid_s[i] = sid[b * Nn + i];
  }
  __syncthreads();

  // top-4 per stage (iterative block argmax; picked nodes get sid=-1)
  for (int s = 0; s < NSn; ++s) {
    for (int j = 0; j < 4; ++j) {
      unsigned long long best = 0ull;
      for (int i = tid; i < Nn; i += 256) {
        if (sid_s[i] == s) {
          unsigned int fbt = __float_as_uint(sc_s[i]);
          fbt = (fbt & 0x80000000u) ? ~fbt : (fbt | 0x80000000u);
          unsigned long long key = ((unsigned long long)fbt << 32) |
                                   (unsigned long long)(unsigned)(Nn - 1 - i);
          if (key > best) best = key;
        }
      }
#pragma unroll
      for (int off = 32; off >= 1; off >>= 1) {
        unsigned long long o = __shfl_xor(best, off);
        if (o > best) best = o;
      }
      __syncthreads();
      if ((tid & 63) == 0) redk[tid >> 6] = best;
      __syncthreads();
      best = redk[0];
      if (redk[1] > best) best = redk[1];
      if (redk[2] > best) best = redk[2];
      if (redk[3] > best) best = redk[3];
      if (tid == 0) {
        int c = s * 4 + j;
        if (best != 0ull) {
          int node = Nn - 1 - (int)(best & 0xFFFFFFFFull);
          cand[c] = node; candv[c] = 1; sid_s[node] = -1;
        } else {
          cand[c] = 0; candv[c] = 0;
        }
      }
      __syncthreads();
    }
  }

  // t_c = adj_row_c @ feat[b]  (fp64 acc; adj rows via uniform scalar streams)
  const float* adjb = adj + ((size_t)b << 18);
  const float* fp = feat + ((size_t)b << 17) + tid;
  const float* ar[20];
#pragma unroll
  for (int c = 0; c < 20; ++c) {
    int row = __builtin_amdgcn_readfirstlane(cand[c]);
    ar[c] = adjb + ((size_t)row << 9);
  }
  double tacc[20];
#pragma unroll
  for (int c = 0; c < 20; ++c) tacc[c] = 0.0;
#pragma unroll 4
  for (int n = 0; n < Nn; ++n) {
    double v = (double)fp[(size_t)n << 8];
#pragma unroll
    for (int c = 0; c < 20; ++c) tacc[c] = fma((double)ar[c][n], v, tacc[c]);
  }
#pragma unroll
  for (int c = 0; c < 20; ++c) tT[tid][c] = (float)tacc[c];
  __syncthreads();

  // x_c = t_c @ W0 (fp64 acc, fp32 operands)
  double xc[20];
#pragma unroll
  for (int c = 0; c < 20; ++c) xc[c] = 0.0;
  const float* wp = W0 + tid;
  for (int f = 0; f < Fn; ++f) {
    double w = (double)wp[(size_t)f << 8];
    float4 t0 = *(const float4*)&tT[f][0];
    float4 t1 = *(const float4*)&tT[f][4];
    float4 t2 = *(const float4*)&tT[f][8];
    float4 t3 = *(const float4*)&tT[f][12];
    float4 t4 = *(const float4*)&tT[f][16];
    xc[0]  = fma((double)t0.x, w, xc[0]);   xc[1]  = fma((double)t0.y, w, xc[1]);
    xc[2]  = fma((double)t0.z, w, xc[2]);   xc[3]  = fma((double)t0.w, w, xc[3]);
    xc[4]  = fma((double)t1.x, w, xc[4]);   xc[5]  = fma((double)t1.y, w, xc[5]);
    xc[6]  = fma((double)t1.z, w, xc[6]);   xc[7]  = fma((double)t1.w, w, xc[7]);
    xc[8]  = fma((double)t2.x, w, xc[8]);   xc[9]  = fma((double)t2.y, w, xc[9]);
    xc[10] = fma((double)t2.z, w, xc[10]);  xc[11] = fma((double)t2.w, w, xc[11]);
    xc[12] = fma((double)t3.x, w, xc[12]);  xc[13] = fma((double)t3.y, w, xc[13]);
    xc[14] = fma((double)t3.z, w, xc[14]);  xc[15] = fma((double)t3.w, w, xc[15]);
    xc[16] = fma((double)t4.x, w, xc[16]);  xc[17] = fma((double)t4.y, w, xc[17]);
    xc[18] = fma((double)t4.z, w, xc[18]);  xc[19] = fma((double)t4.w, w, xc[19]);
  }
#pragma unroll
  for (int c = 0; c < 20; ++c) xb[c][tid] = (float)xc[c];
  __syncthreads();

  // exact LN0 + score per candidate (reference two-pass variance)
  const float b0t = b0[tid], g0t = g0[tid], be0t = be0[tid];
  for (int c = 0; c < 20; ++c) {
    float xv = xb[c][tid] + b0t;
    float m = brs(xv) * (1.0f / Hn);
    float d = xv - m;
    float var = brs(d * d) * (1.0f / Hn);
    float rstd = 1.0f / sqrtf(var + EPS);
    float zz = d * rstd * g0t + be0t;
    float sc = brs(fmaxf(zz, 0.f));
    if (tid == 0) { cm[c] = m; cr[c] = rstd; csc[c] = sc; }
  }
  __syncthreads();

  if (tid == 0) {
#pragma unroll
    for (int s = 0; s < NSn; ++s) {
      int wsl = s * 4;
      float bestv = 0.f; int bestn = 0; bool any = false;
      for (int j = 0; j < 4; ++j) {
        int c = s * 4 + j;
        if (!candv[c]) continue;
        float v = csc[c]; int node = cand[c];
        if (!any || v > bestv || (v == bestv && node < bestn)) {
          any = true; bestv = v; bestn = node; wsl = c;
        }
      }
      winslot[s] = wsl;
    }
  }
  __syncthreads();

  // tail
  const float b1t = b1[tid], g1t = g1[tid], be1t = be1[tid];
  float xsum = 0.f;
  for (int s = 0; s < NSn; ++s) {
    int c = winslot[s];
    float xv = xb[c][tid] + b0t;
    float z0 = (xv - cm[c]) * cr[c] * g0t + be0t;
    float o = fmaxf(z0, 0.f) + b1t;
    float m1 = brs(o) * (1.0f / Hn);
    float d1 = o - m1;
    float v1 = brs(d1 * d1) * (1.0f / Hn);
    float z1 = d1 * (1.0f / sqrtf(v1 + EPS)) * g1t + be1t;
    xsum += fmaxf(z1, 0.f);
  }
  xs[tid] = xsum;
  __syncthreads();
  float y = 0.f;
  for (int h = 0; h < Hn; h += 4) {
    float4 xv4 = *(const float4*)&xs[h];
    y = fmaf(xv4.x, W2[(size_t)h * Hn + tid], y);
    y = fmaf(xv4.y, W2[(size_t)(h + 1) * Hn + tid], y);
    y = fmaf(xv4.z, W2[(size_t)(h + 2) * Hn + tid], y);
    y = fmaf(xv4.w, W2[(size_t)(h + 3) * Hn + tid], y);
  }
  y += b2[tid];
  float m2 = brs(y) * (1.0f / Hn);
  float d2 = y - m2;
  float v2 = brs(d2 * d2) * (1.0f / Hn);
  float z2 = d2 * (1.0f / sqrtf(v2 + EPS)) * g2[tid] + be2[tid];
  float p = fmaxf(z2, 0.f) * fcW[tid];
  float tot = brs(p);
  if (tid == 0) out[b] = tot + fcb[0];
}

// ---------------------------------------------------------------------------
extern "C" void kernel_launch(void* const* d_in, const int* in_sizes, int n_in,
                              void* d_out, int out_size, void* d_ws, size_t ws_size,
                              hipStream_t stream)
{
  (void)in_sizes; (void)n_in; (void)out_size; (void)ws_size;
  const float* adj  = (const float*)d_in[0];
  const float* feat = (const float*)d_in[1];
  const int*   sid  = (const int*)d_in[2];
  const float* W0   = (const float*)d_in[3];
  const float* b0   = (const float*)d_in[4];
  const float* b1   = (const float*)d_in[5];
  const float* W2   = (const float*)d_in[6];
  const float* b2   = (const float*)d_in[7];
  const float* g0   = (const float*)d_in[8];
  const float* be0  = (const float*)d_in[9];
  const float* g1   = (const float*)d_in[10];
  const float* be1  = (const float*)d_in[11];
  const float* g2   = (const float*)d_in[12];
  const float* be2  = (const float*)d_in[13];
  const float* fcW  = (const float*)d_in[14];
  const float* fcb  = (const float*)d_in[15];
  float* out = (float*)d_out;

  // ws: supT bf16 [B][H][N] (67,108,864 B) | W0T bf16 (131,072 B) | scores f32 (524,288 B)
  unsigned short* supT = (unsigned short*)d_ws;
  unsigned short* W0T  = (unsigned short*)((char*)d_ws + 67108864);
  float* scores        = (float*)((char*)d_ws + 67108864 + 131072);

  k0_prep<<<dim3(256), dim3(256), 0, stream>>>(W0, W0T);
  k1_support<<<dim3(2048), dim3(256), 0, stream>>>(feat, W0T, supT);
  k2_scores<<<dim3(2048), dim3(256), 0, stream>>>(adj, supT, b0, g0, be0, scores);
  k3_final<<<dim3(256), dim3(256), 0, stream>>>(adj, feat, scores, sid,
      W0, b0, b1, W2, b2, g0, be0, g1, be1, g2, be2, fcW, fcb, out);
}

// Round 3
// 738.233 us; speedup vs baseline: 1.3244x; 1.1742x over previous
//
#include <hip/hip_runtime.h>
#include <stdint.h>

#define Bn 256
#define Nn 512
#define Fn 256
#define Hn 256
#define NSn 5
#define EPS 1e-5f
#define LSTR 56   // LDS row stride in ushorts (112B: 16B-aligned, uniform bank spread)

typedef __attribute__((ext_vector_type(8))) short bf16x8;
typedef __attribute__((ext_vector_type(4))) float f32x4;

__device__ __forceinline__ unsigned short f2bf(float x) {
  unsigned int u = __float_as_uint(x);
  u += 0x7FFFu + ((u >> 16) & 1u);          // RTNE
  return (unsigned short)(u >> 16);
}
__device__ __forceinline__ unsigned int pack2bf(float a, float b) {
  return (unsigned int)f2bf(a) | ((unsigned int)f2bf(b) << 16);
}

// ---------------------------------------------------------------------------
// k0: W0T[h][f] = bf16(W0[f][h]) via LDS tile transpose (coalesced R/W).
// Grid 16 blocks = 4x4 tiles of 64x64.
// ---------------------------------------------------------------------------
__global__ __launch_bounds__(256) void k0_prep(const float* __restrict__ W0,
                                               unsigned short* __restrict__ W0T) {
  __shared__ float tile[64][68];
  const int tid = (int)threadIdx.x;
  const int ti = blockIdx.x >> 2, tj = blockIdx.x & 3;   // f-tile, h-tile
#pragma unroll
  for (int q = 0; q < 4; ++q) {
    int s = tid + 256 * q;              // 0..1023
    int r = s >> 4, c4 = s & 15;        // f-row, 4-col group
    *(float4*)&tile[r][c4 * 4] =
        *(const float4*)(W0 + (size_t)(ti * 64 + r) * Hn + tj * 64 + c4 * 4);
  }
  __syncthreads();
#pragma unroll
  for (int q = 0; q < 4; ++q) {
    int s = tid + 256 * q;
    int hh = s >> 4, fq = s & 15;
    int ff = fq * 4;
    float t0 = tile[ff + 0][hh], t1 = tile[ff + 1][hh];
    float t2 = tile[ff + 2][hh], t3 = tile[ff + 3][hh];
    *(uint2*)(W0T + (size_t)(tj * 64 + hh) * Fn + ti * 64 + ff) =
        make_uint2(pack2bf(t0, t1), pack2bf(t2, t3));
  }
}

// ---------------------------------------------------------------------------
// k1: supT[b][h][node] = bf16( (features @ W0)[node][h] )  via MFMA bf16.
// BM=64 rows, full 256 cols. 4 waves, each owns a 64-col strip (4x4 frag grid).
// ---------------------------------------------------------------------------
__global__ __launch_bounds__(256) void k1_support(
    const float* __restrict__ feat, const unsigned short* __restrict__ W0T,
    unsigned short* __restrict__ supT)
{
  __shared__ __align__(16) unsigned short As[64 * LSTR];
  __shared__ __align__(16) unsigned short Bs[256 * LSTR];
  const int tid = (int)threadIdx.x;
  const int wv = tid >> 6, lane = tid & 63;
  const int m0 = blockIdx.x * 64;
  f32x4 acc[4][4];
  const f32x4 z4 = {0.f, 0.f, 0.f, 0.f};
#pragma unroll
  for (int i = 0; i < 4; ++i)
#pragma unroll
    for (int j = 0; j < 4; ++j) acc[i][j] = z4;

  const int ar = tid >> 2, ac = tid & 3;
  for (int k0 = 0; k0 < Fn; k0 += 32) {
    const float* ap = feat + (size_t)(m0 + ar) * Fn + k0 + ac * 4;
    float4 v0 = *(const float4*)ap;
    float4 v1 = *(const float4*)(ap + 16);
    *(uint2*)&As[ar * LSTR + ac * 4] =
        make_uint2(pack2bf(v0.x, v0.y), pack2bf(v0.z, v0.w));
    *(uint2*)&As[ar * LSTR + 16 + ac * 4] =
        make_uint2(pack2bf(v1.x, v1.y), pack2bf(v1.z, v1.w));
#pragma unroll
    for (int q = 0; q < 4; ++q) {
      int s = q * 256 + tid;
      int h = s >> 2, c = s & 3;
      *(uint4*)&Bs[h * LSTR + c * 8] =
          *(const uint4*)(W0T + (size_t)h * Fn + k0 + c * 8);
    }
    __syncthreads();
    bf16x8 af[4], bfr[4];
#pragma unroll
    for (int i = 0; i < 4; ++i) {
      af[i]  = *(const bf16x8*)&As[(i * 16 + (lane & 15)) * LSTR + (lane >> 4) * 8];
      bfr[i] = *(const bf16x8*)&Bs[(wv * 64 + i * 16 + (lane & 15)) * LSTR + (lane >> 4) * 8];
    }
#pragma unroll
    for (int mi = 0; mi < 4; ++mi)
#pragma unroll
      for (int nt = 0; nt < 4; ++nt)
        acc[mi][nt] = __builtin_amdgcn_mfma_f32_16x16x32_bf16(af[mi], bfr[nt], acc[mi][nt], 0, 0, 0);
    __syncthreads();
  }
  // epilogue: C row=(lane>>4)*4+reg (node), col=lane&15 (h) -> supT[b][h][node]
  const int b = m0 >> 9;
  const int nodebase = m0 & 511;
  unsigned short* outb = supT + ((size_t)b << 17);
#pragma unroll
  for (int mi = 0; mi < 4; ++mi)
#pragma unroll
    for (int nt = 0; nt < 4; ++nt) {
      int h = wv * 64 + nt * 16 + (lane & 15);
      int node = nodebase + mi * 16 + (lane >> 4) * 4;
      *(uint2*)(outb + (size_t)h * Nn + node) =
          make_uint2(pack2bf(acc[mi][nt][0], acc[mi][nt][1]),
                     pack2bf(acc[mi][nt][2], acc[mi][nt][3]));
    }
}

// ---------------------------------------------------------------------------
// k2: per batch, scores[node] = sum_h relu(LN0(adj@sup + b0)) via MFMA bf16.
// BM=64, full 256 cols; fused LN epilogue; x never stored.
// Block order: b = id>>3, mc = id&7 -> the 8 blocks of a batch are temporally
// adjacent (supT[b] re-reads hit L3/L2 in flight instead of HBM).
// ---------------------------------------------------------------------------
__global__ __launch_bounds__(256) void k2_scores(
    const float* __restrict__ adj, const unsigned short* __restrict__ supT,
    const float* __restrict__ b0, const float* __restrict__ g0,
    const float* __restrict__ be0, float* __restrict__ scores)
{
  __shared__ __align__(16) unsigned short As[64 * LSTR];
  __shared__ __align__(16) unsigned short Bs[256 * LSTR];
  const int tid = (int)threadIdx.x;
  const int wv = tid >> 6, lane = tid & 63;
  const int b = blockIdx.x >> 3;
  const int m0 = (blockIdx.x & 7) * 64;
  const float* adjb = adj + ((size_t)b << 18);
  const unsigned short* supb = supT + ((size_t)b << 17);
  f32x4 acc[4][4];
  const f32x4 z4 = {0.f, 0.f, 0.f, 0.f};
#pragma unroll
  for (int i = 0; i < 4; ++i)
#pragma unroll
    for (int j = 0; j < 4; ++j) acc[i][j] = z4;

  const int ar = tid >> 2, ac = tid & 3;
  for (int k0 = 0; k0 < Nn; k0 += 32) {
    const float* ap = adjb + (size_t)(m0 + ar) * Nn + k0 + ac * 4;
    float4 v0 = *(const float4*)ap;
    float4 v1 = *(const float4*)(ap + 16);
    *(uint2*)&As[ar * LSTR + ac * 4] =
        make_uint2(pack2bf(v0.x, v0.y), pack2bf(v0.z, v0.w));
    *(uint2*)&As[ar * LSTR + 16 + ac * 4] =
        make_uint2(pack2bf(v1.x, v1.y), pack2bf(v1.z, v1.w));
#pragma unroll
    for (int q = 0; q < 4; ++q) {
      int s = q * 256 + tid;
      int h = s >> 2, c = s & 3;
      *(uint4*)&Bs[h * LSTR + c * 8] =
          *(const uint4*)(supb + (size_t)h * Nn + k0 + c * 8);
    }
    __syncthreads();
    bf16x8 af[4], bfr[4];
#pragma unroll
    for (int i = 0; i < 4; ++i) {
      af[i]  = *(const bf16x8*)&As[(i * 16 + (lane & 15)) * LSTR + (lane >> 4) * 8];
      bfr[i] = *(const bf16x8*)&Bs[(wv * 64 + i * 16 + (lane & 15)) * LSTR + (lane >> 4) * 8];
    }
#pragma unroll
    for (int mi = 0; mi < 4; ++mi)
#pragma unroll
      for (int nt = 0; nt < 4; ++nt)
        acc[mi][nt] = __builtin_amdgcn_mfma_f32_16x16x32_bf16(af[mi], bfr[nt], acc[mi][nt], 0, 0, 0);
    __syncthreads();
  }

  // Epilogue: LN0 + relu + row sum. red: [0..255]=s1[row][wv],[256..511]=s2,[512..767]=sc
  float* red = (float*)As;
  float b0v[4], g0v[4], be0v[4];
#pragma unroll
  for (int nt = 0; nt < 4; ++nt) {
    int col = wv * 64 + nt * 16 + (lane & 15);
    b0v[nt] = b0[col]; g0v[nt] = g0[col]; be0v[nt] = be0[col];
  }
#pragma unroll
  for (int mi = 0; mi < 4; ++mi)
#pragma unroll
    for (int rg = 0; rg < 4; ++rg) {
      float s1 = 0.f, s2 = 0.f;
#pragma unroll
      for (int nt = 0; nt < 4; ++nt) {
        float x = acc[mi][nt][rg] + b0v[nt];
        s1 += x; s2 += x * x;
      }
#pragma unroll
      for (int off = 8; off >= 1; off >>= 1) {
        s1 += __shfl_xor(s1, off);
        s2 += __shfl_xor(s2, off);
      }
      if ((lane & 15) == 0) {
        int row = mi * 16 + (lane >> 4) * 4 + rg;
        red[row * 4 + wv] = s1;
        red[256 + row * 4 + wv] = s2;
      }
    }
  __syncthreads();
#pragma unroll
  for (int mi = 0; mi < 4; ++mi)
#pragma unroll
    for (int rg = 0; rg < 4; ++rg) {
      int row = mi * 16 + (lane >> 4) * 4 + rg;
      float s1 = red[row*4] + red[row*4+1] + red[row*4+2] + red[row*4+3];
      float s2 = red[256+row*4] + red[256+row*4+1] + red[256+row*4+2] + red[256+row*4+3];
      float m = s1 * (1.0f / Hn);
      float var = s2 * (1.0f / Hn) - m * m;
      float rstd = 1.0f / sqrtf(var + EPS);
      float sc = 0.f;
#pragma unroll
      for (int nt = 0; nt < 4; ++nt) {
        float x = acc[mi][nt][rg] + b0v[nt];
        float zz = (x - m) * rstd * g0v[nt] + be0v[nt];
        sc += fmaxf(zz, 0.f);
      }
#pragma unroll
      for (int off = 8; off >= 1; off >>= 1) sc += __shfl_xor(sc, off);
      if ((lane & 15) == 0) red[512 + row * 4 + wv] = sc;
    }
  __syncthreads();
  if (tid < 64) {
    float s = red[512+tid*4] + red[512+tid*4+1] + red[512+tid*4+2] + red[512+tid*4+3];
    scores[b * Nn + m0 + tid] = s;
  }
}

// ---------------------------------------------------------------------------
// k3b: grid (256 batches x 4 n-chunks). Per block: top-4 selection per stage
// (redundant but deterministic across chunks), then fp64 partials of
// t_c = adj_row_c @ feat[b] over this block's n-chunk. feat read exactly once.
// ---------------------------------------------------------------------------
__global__ __launch_bounds__(256) void k3b_part(
    const float* __restrict__ adj, const float* __restrict__ feat,
    const float* __restrict__ scores, const int* __restrict__ sid,
    int* __restrict__ candbuf, double* __restrict__ px)
{
  __shared__ float sc_s[Nn];
  __shared__ int sid_s[Nn];
  __shared__ __align__(16) float adjs[20][128];
  __shared__ unsigned long long redk[4];
  __shared__ int cand[20], candv[20];
  const int tid = (int)threadIdx.x;
  const int b = blockIdx.x >> 2, ch = blockIdx.x & 3;

  for (int i = tid; i < Nn; i += 256) {
    sc_s[i] = scores[b * Nn + i];
    sid_s[i] = sid[b * Nn + i];
  }
  __syncthreads();

  for (int s = 0; s < NSn; ++s)
    for (int j = 0; j < 4; ++j) {
      unsigned long long best = 0ull;
      for (int i = tid; i < Nn; i += 256)
        if (sid_s[i] == s) {
          unsigned int fb = __float_as_uint(sc_s[i]);
          fb = (fb & 0x80000000u) ? ~fb : (fb | 0x80000000u);
          unsigned long long key = ((unsigned long long)fb << 32) |
                                   (unsigned long long)(unsigned)(Nn - 1 - i);
          if (key > best) best = key;
        }
#pragma unroll
      for (int off = 32; off >= 1; off >>= 1) {
        unsigned long long o = __shfl_xor(best, off);
        if (o > best) best = o;
      }
      if ((tid & 63) == 0) redk[tid >> 6] = best;
      __syncthreads();
      if (tid == 0) {
        unsigned long long bb = redk[0];
        if (redk[1] > bb) bb = redk[1];
        if (redk[2] > bb) bb = redk[2];
        if (redk[3] > bb) bb = redk[3];
        int c = s * 4 + j;
        if (bb != 0ull) {
          int node = Nn - 1 - (int)(bb & 0xFFFFFFFFull);
          cand[c] = node; candv[c] = 1; sid_s[node] = -1;
        } else {
          cand[c] = 0; candv[c] = 0;
        }
      }
      __syncthreads();
    }

  if (ch == 0 && tid < 20) {
    candbuf[b * 40 + tid] = cand[tid];
    candbuf[b * 40 + 20 + tid] = candv[tid];
  }

  // stage the 20 candidate adj-row slices for this n-chunk
  const float* adjb = adj + ((size_t)b << 18);
  for (int idx = tid; idx < 20 * 128; idx += 256) {
    int c = idx >> 7, n = idx & 127;
    adjs[c][n] = adjb[((size_t)cand[c] << 9) + ch * 128 + n];
  }
  __syncthreads();

  double t[20];
#pragma unroll
  for (int c = 0; c < 20; ++c) t[c] = 0.0;
  const float* fp = feat + ((size_t)b << 17) + (((size_t)ch * 128) << 8) + tid;
  for (int n0 = 0; n0 < 128; n0 += 4) {
    double d0 = (double)fp[(size_t)(n0 + 0) << 8];
    double d1 = (double)fp[(size_t)(n0 + 1) << 8];
    double d2 = (double)fp[(size_t)(n0 + 2) << 8];
    double d3 = (double)fp[(size_t)(n0 + 3) << 8];
#pragma unroll
    for (int c = 0; c < 20; ++c) {
      float4 av = *(const float4*)&adjs[c][n0];
      t[c] += (double)av.x * d0 + (double)av.y * d1 +
              (double)av.z * d2 + (double)av.w * d3;
    }
  }
  double* pxb = px + ((size_t)(b * 4 + ch) * 20) * 256 + tid;
#pragma unroll
  for (int c = 0; c < 20; ++c) pxb[(size_t)c * 256] = t[c];
}

// ---------------------------------------------------------------------------
__device__ __forceinline__ float brs(float v) {
  __shared__ float sb[4];
#pragma unroll
  for (int off = 32; off >= 1; off >>= 1) v += __shfl_xor(v, off);
  __syncthreads();
  if ((threadIdx.x & 63) == 0) sb[threadIdx.x >> 6] = v;
  __syncthreads();
  return sb[0] + sb[1] + sb[2] + sb[3];
}

// ---------------------------------------------------------------------------
// k3c: one block/batch. Reduce t partials, x = t @ W0 (fp32), exact LN0
// scores per candidate (per-wave parallel), winner per stage, then the tail.
// ---------------------------------------------------------------------------
__global__ __launch_bounds__(256) void k3c_final(
    const double* __restrict__ px, const int* __restrict__ candbuf,
    const float* __restrict__ W0, const float* __restrict__ b0,
    const float* __restrict__ b1, const float* __restrict__ W2,
    const float* __restrict__ b2, const float* __restrict__ g0,
    const float* __restrict__ be0, const float* __restrict__ g1,
    const float* __restrict__ be1, const float* __restrict__ g2,
    const float* __restrict__ be2, const float* __restrict__ fcW,
    const float* __restrict__ fcb, float* __restrict__ out)
{
  __shared__ __align__(16) float tfT[Fn * 20];   // [f][c]
  __shared__ float xb[20][Hn];
  __shared__ float b0s[Hn], g0s[Hn], be0s[Hn];
  __shared__ float cm[20], cr[20], csc[20];
  __shared__ int candL[20], candvL[20], winslot[NSn];
  __shared__ float xs[Hn];
  const int tid = (int)threadIdx.x;
  const int b = blockIdx.x;

  if (tid < 20) {
    candL[tid] = candbuf[b * 40 + tid];
    candvL[tid] = candbuf[b * 40 + 20 + tid];
  }
  b0s[tid] = b0[tid]; g0s[tid] = g0[tid]; be0s[tid] = be0[tid];
  // reduce t over 4 chunks (fp64) -> tfT[f=tid][c] fp32
  {
    const double* pxb = px + ((size_t)b * 4 * 20) * 256 + tid;
#pragma unroll
    for (int c = 0; c < 20; ++c) {
      double t = pxb[(size_t)c * 256] + pxb[(size_t)(20 + c) * 256] +
                 pxb[(size_t)(40 + c) * 256] + pxb[(size_t)(60 + c) * 256];
      tfT[tid * 20 + c] = (float)t;
    }
  }
  __syncthreads();

  // x_c[h=tid] = sum_f tfT[f][c] * W0[f][h]   (fp32)
  {
    float xc[20];
#pragma unroll
    for (int c = 0; c < 20; ++c) xc[c] = 0.f;
    for (int f = 0; f < Fn; ++f) {
      float w = W0[(size_t)f * Hn + tid];
      const float* tp = &tfT[f * 20];
      float4 t0 = *(const float4*)(tp);
      float4 t1 = *(const float4*)(tp + 4);
      float4 t2 = *(const float4*)(tp + 8);
      float4 t3 = *(const float4*)(tp + 12);
      float4 t4 = *(const float4*)(tp + 16);
      xc[0] = fmaf(t0.x, w, xc[0]);   xc[1] = fmaf(t0.y, w, xc[1]);
      xc[2] = fmaf(t0.z, w, xc[2]);   xc[3] = fmaf(t0.w, w, xc[3]);
      xc[4] = fmaf(t1.x, w, xc[4]);   xc[5] = fmaf(t1.y, w, xc[5]);
      xc[6] = fmaf(t1.z, w, xc[6]);   xc[7] = fmaf(t1.w, w, xc[7]);
      xc[8] = fmaf(t2.x, w, xc[8]);   xc[9] = fmaf(t2.y, w, xc[9]);
      xc[10] = fmaf(t2.z, w, xc[10]); xc[11] = fmaf(t2.w, w, xc[11]);
      xc[12] = fmaf(t3.x, w, xc[12]); xc[13] = fmaf(t3.y, w, xc[13]);
      xc[14] = fmaf(t3.z, w, xc[14]); xc[15] = fmaf(t3.w, w, xc[15]);
      xc[16] = fmaf(t4.x, w, xc[16]); xc[17] = fmaf(t4.y, w, xc[17]);
      xc[18] = fmaf(t4.z, w, xc[18]); xc[19] = fmaf(t4.w, w, xc[19]);
    }
#pragma unroll
    for (int c = 0; c < 20; ++c) xb[c][tid] = xc[c];
  }
  __syncthreads();

  // exact LN0 score per candidate: wave wv handles candidates wv, wv+4, ...
  {
    const int wv = tid >> 6, lane = tid & 63;
    for (int c = wv; c < 20; c += 4) {
      float v0 = xb[c][lane] + b0s[lane];
      float v1 = xb[c][lane + 64] + b0s[lane + 64];
      float v2 = xb[c][lane + 128] + b0s[lane + 128];
      float v3 = xb[c][lane + 192] + b0s[lane + 192];
      float s = v0 + v1 + v2 + v3;
#pragma unroll
      for (int off = 32; off >= 1; off >>= 1) s += __shfl_xor(s, off);
      float m = s * (1.0f / Hn);
      float d0 = v0 - m, d1 = v1 - m, d2 = v2 - m, d3 = v3 - m;
      float s2 = d0 * d0 + d1 * d1 + d2 * d2 + d3 * d3;
#pragma unroll
      for (int off = 32; off >= 1; off >>= 1) s2 += __shfl_xor(s2, off);
      float rstd = 1.0f / sqrtf(s2 * (1.0f / Hn) + EPS);
      float sc = fmaxf(d0 * rstd * g0s[lane] + be0s[lane], 0.f) +
                 fmaxf(d1 * rstd * g0s[lane + 64] + be0s[lane + 64], 0.f) +
                 fmaxf(d2 * rstd * g0s[lane + 128] + be0s[lane + 128], 0.f) +
                 fmaxf(d3 * rstd * g0s[lane + 192] + be0s[lane + 192], 0.f);
#pragma unroll
      for (int off = 32; off >= 1; off >>= 1) sc += __shfl_xor(sc, off);
      if (lane == 0) { cm[c] = m; cr[c] = rstd; csc[c] = sc; }
    }
  }
  __syncthreads();

  if (tid == 0) {
#pragma unroll
    for (int s = 0; s < NSn; ++s) {
      int wsl = s * 4;
      float bestv = 0.f; int bestn = 0; bool any = false;
      for (int j = 0; j < 4; ++j) {
        int c = s * 4 + j;
        if (!candvL[c]) continue;
        float v = csc[c]; int node = candL[c];
        if (!any || v > bestv || (v == bestv && node < bestn)) {
          any = true; bestv = v; bestn = node; wsl = c;
        }
      }
      winslot[s] = wsl;
    }
  }
  __syncthreads();

  // tail
  const float b0t = b0s[tid], g0t = g0s[tid], be0t = be0s[tid];
  const float b1t = b1[tid], g1t = g1[tid], be1t = be1[tid];
  float xsum = 0.f;
  for (int s = 0; s < NSn; ++s) {
    int c = winslot[s];
    float xv = xb[c][tid] + b0t;
    float z0 = (xv - cm[c]) * cr[c] * g0t + be0t;
    float o = fmaxf(z0, 0.f) + b1t;
    float m1 = brs(o) * (1.0f / Hn);
    float d1 = o - m1;
    float v1 = brs(d1 * d1) * (1.0f / Hn);
    float z1 = d1 * (1.0f / sqrtf(v1 + EPS)) * g1t + be1t;
    xsum += fmaxf(z1, 0.f);
  }
  xs[tid] = xsum;
  __syncthreads();
  float y = 0.f;
  for (int h = 0; h < Hn; h += 4) {
    float4 xv4 = *(const float4*)&xs[h];
    y = fmaf(xv4.x, W2[(size_t)h * Hn + tid], y);
    y = fmaf(xv4.y, W2[(size_t)(h + 1) * Hn + tid], y);
    y = fmaf(xv4.z, W2[(size_t)(h + 2) * Hn + tid], y);
    y = fmaf(xv4.w, W2[(size_t)(h + 3) * Hn + tid], y);
  }
  y += b2[tid];
  float m2 = brs(y) * (1.0f / Hn);
  float d2 = y - m2;
  float v2 = brs(d2 * d2) * (1.0f / Hn);
  float z2 = d2 * (1.0f / sqrtf(v2 + EPS)) * g2[tid] + be2[tid];
  float p = fmaxf(z2, 0.f) * fcW[tid];
  float tot = brs(p);
  if (tid == 0) out[b] = tot + fcb[0];
}

// ---------------------------------------------------------------------------
extern "C" void kernel_launch(void* const* d_in, const int* in_sizes, int n_in,
                              void* d_out, int out_size, void* d_ws, size_t ws_size,
                              hipStream_t stream)
{
  (void)in_sizes; (void)n_in; (void)out_size; (void)ws_size;
  const float* adj  = (const float*)d_in[0];
  const float* feat = (const float*)d_in[1];
  const int*   sid  = (const int*)d_in[2];
  const float* W0   = (const float*)d_in[3];
  const float* b0   = (const float*)d_in[4];
  const float* b1   = (const float*)d_in[5];
  const float* W2   = (const float*)d_in[6];
  const float* b2   = (const float*)d_in[7];
  const float* g0   = (const float*)d_in[8];
  const float* be0  = (const float*)d_in[9];
  const float* g1   = (const float*)d_in[10];
  const float* be1  = (const float*)d_in[11];
  const float* g2   = (const float*)d_in[12];
  const float* be2  = (const float*)d_in[13];
  const float* fcW  = (const float*)d_in[14];
  const float* fcb  = (const float*)d_in[15];
  float* out = (float*)d_out;

  // ws: supT bf16 [B][H][N] 67,108,864 | W0T bf16 131,072 | scores f32 524,288
  //     | candbuf int 40,960 | px f64 41,943,040   (total ~104.7 MB)
  unsigned short* supT = (unsigned short*)d_ws;
  unsigned short* W0T  = (unsigned short*)((char*)d_ws + 67108864);
  float* scores        = (float*)((char*)d_ws + 67239936);
  int* candbuf         = (int*)((char*)d_ws + 67764224);
  double* px           = (double*)((char*)d_ws + 67805184);

  k0_prep<<<dim3(16), dim3(256), 0, stream>>>(W0, W0T);
  k1_support<<<dim3(2048), dim3(256), 0, stream>>>(feat, W0T, supT);
  k2_scores<<<dim3(2048), dim3(256), 0, stream>>>(adj, supT, b0, g0, be0, scores);
  k3b_part<<<dim3(1024), dim3(256), 0, stream>>>(adj, feat, scores, sid, candbuf, px);
  k3c_final<<<dim3(256), dim3(256), 0, stream>>>(px, candbuf,
      W0, b0, b1, W2, b2, g0, be0, g1, be1, g2, be2, fcW, fcb, out);
}

// Round 4
// 701.853 us; speedup vs baseline: 1.3930x; 1.0518x over previous
//
#include <hip/hip_runtime.h>
#include <stdint.h>

#define Bn 256
#define Nn 512
#define Fn 256
#define Hn 256
#define NSn 5
#define EPS 1e-5f
#define LSTR 56   // LDS row stride in ushorts (112B: 16B-aligned, 2-lane bank groups)

typedef __attribute__((ext_vector_type(8))) short bf16x8;
typedef __attribute__((ext_vector_type(4))) float f32x4;

__device__ __forceinline__ unsigned short f2bf(float x) {
  unsigned int u = __float_as_uint(x);
  u += 0x7FFFu + ((u >> 16) & 1u);          // RTNE
  return (unsigned short)(u >> 16);
}
__device__ __forceinline__ unsigned int pack2bf(float a, float b) {
  return (unsigned int)f2bf(a) | ((unsigned int)f2bf(b) << 16);
}

// ---------------------------------------------------------------------------
// k0: W0T[h][f] = bf16(W0[f][h]) via LDS tile transpose (coalesced R/W).
// ---------------------------------------------------------------------------
__global__ __launch_bounds__(256) void k0_prep(const float* __restrict__ W0,
                                               unsigned short* __restrict__ W0T) {
  __shared__ float tile[64][68];
  const int tid = (int)threadIdx.x;
  const int ti = blockIdx.x >> 2, tj = blockIdx.x & 3;   // f-tile, h-tile
#pragma unroll
  for (int q = 0; q < 4; ++q) {
    int s = tid + 256 * q;
    int r = s >> 4, c4 = s & 15;
    *(float4*)&tile[r][c4 * 4] =
        *(const float4*)(W0 + (size_t)(ti * 64 + r) * Hn + tj * 64 + c4 * 4);
  }
  __syncthreads();
#pragma unroll
  for (int q = 0; q < 4; ++q) {
    int s = tid + 256 * q;
    int hh = s >> 4, fq = s & 15;
    int ff = fq * 4;
    float t0 = tile[ff + 0][hh], t1 = tile[ff + 1][hh];
    float t2 = tile[ff + 2][hh], t3 = tile[ff + 3][hh];
    *(uint2*)(W0T + (size_t)(tj * 64 + hh) * Fn + ti * 64 + ff) =
        make_uint2(pack2bf(t0, t1), pack2bf(t2, t3));
  }
}

// ---------------------------------------------------------------------------
// k1: supT[b][h][node] = bf16((features@W0)[node][h]) via MFMA bf16.
// 128x256 tile, 512 threads = 8 waves (2 row-halves x 4 col-quarters),
// wave tile 64x64 = acc[4][4] (proven mapping). K=256, BK=32.
// ---------------------------------------------------------------------------
__global__ __launch_bounds__(512) void k1_support(
    const float* __restrict__ feat, const unsigned short* __restrict__ W0T,
    unsigned short* __restrict__ supT)
{
  __shared__ __align__(16) unsigned short As[128 * LSTR];
  __shared__ __align__(16) unsigned short Bs[256 * LSTR];
  const int tid = (int)threadIdx.x;
  const int wv = tid >> 6, lane = tid & 63;
  const int wr = wv >> 2, wc = wv & 3;
  const int m0 = blockIdx.x * 128;
  f32x4 acc[4][4];
  const f32x4 z4 = {0.f, 0.f, 0.f, 0.f};
#pragma unroll
  for (int i = 0; i < 4; ++i)
#pragma unroll
    for (int j = 0; j < 4; ++j) acc[i][j] = z4;

  const int ar = tid >> 2, ac = tid & 3;   // A: row 0..127, col-group (8 elems)
  for (int k0 = 0; k0 < Fn; k0 += 32) {
    {
      const float* ap = feat + (size_t)(m0 + ar) * Fn + k0 + ac * 8;
      float4 v0 = *(const float4*)ap;
      float4 v1 = *(const float4*)(ap + 4);
      uint4 pk = make_uint4(pack2bf(v0.x, v0.y), pack2bf(v0.z, v0.w),
                            pack2bf(v1.x, v1.y), pack2bf(v1.z, v1.w));
      *(uint4*)&As[ar * LSTR + ac * 8] = pk;
    }
#pragma unroll
    for (int q = 0; q < 2; ++q) {
      int s = tid + 512 * q;              // 0..1023
      int r = s >> 2, cg = s & 3;         // h-row 0..255
      *(uint4*)&Bs[r * LSTR + cg * 8] =
          *(const uint4*)(W0T + (size_t)r * Fn + k0 + cg * 8);
    }
    __syncthreads();
    bf16x8 af[4], bfr[4];
#pragma unroll
    for (int i = 0; i < 4; ++i) {
      af[i]  = *(const bf16x8*)&As[(wr * 64 + i * 16 + (lane & 15)) * LSTR + (lane >> 4) * 8];
      bfr[i] = *(const bf16x8*)&Bs[(wc * 64 + i * 16 + (lane & 15)) * LSTR + (lane >> 4) * 8];
    }
#pragma unroll
    for (int mi = 0; mi < 4; ++mi)
#pragma unroll
      for (int nt = 0; nt < 4; ++nt)
        acc[mi][nt] = __builtin_amdgcn_mfma_f32_16x16x32_bf16(af[mi], bfr[nt], acc[mi][nt], 0, 0, 0);
    __syncthreads();
  }
  const int b = m0 >> 9;
  const int nodebase = (m0 & 511) + wr * 64;
  unsigned short* outb = supT + ((size_t)b << 17);
#pragma unroll
  for (int mi = 0; mi < 4; ++mi)
#pragma unroll
    for (int nt = 0; nt < 4; ++nt) {
      int h = wc * 64 + nt * 16 + (lane & 15);
      int node = nodebase + mi * 16 + (lane >> 4) * 4;
      *(uint2*)(outb + (size_t)h * Nn + node) =
          make_uint2(pack2bf(acc[mi][nt][0], acc[mi][nt][1]),
                     pack2bf(acc[mi][nt][2], acc[mi][nt][3]));
    }
}

// ---------------------------------------------------------------------------
// k2: per batch, scores[node] = sum_h relu(LN0(adj@sup + b0)) via MFMA bf16.
// 128x256 tile, 512 threads / 8 waves; fused LN epilogue; x never stored.
// b = id>>2 keeps the 4 blocks of a batch temporally adjacent (supT reuse).
// ---------------------------------------------------------------------------
__global__ __launch_bounds__(512) void k2_scores(
    const float* __restrict__ adj, const unsigned short* __restrict__ supT,
    const float* __restrict__ b0, const float* __restrict__ g0,
    const float* __restrict__ be0, float* __restrict__ scores)
{
  __shared__ __align__(16) unsigned short As[128 * LSTR];
  __shared__ __align__(16) unsigned short Bs[256 * LSTR];
  const int tid = (int)threadIdx.x;
  const int wv = tid >> 6, lane = tid & 63;
  const int wr = wv >> 2, wc = wv & 3;
  const int b = blockIdx.x >> 2;
  const int m0 = (blockIdx.x & 3) * 128;
  const float* adjb = adj + ((size_t)b << 18);
  const unsigned short* supb = supT + ((size_t)b << 17);
  f32x4 acc[4][4];
  const f32x4 z4 = {0.f, 0.f, 0.f, 0.f};
#pragma unroll
  for (int i = 0; i < 4; ++i)
#pragma unroll
    for (int j = 0; j < 4; ++j) acc[i][j] = z4;

  const int ar = tid >> 2, ac = tid & 3;
  for (int k0 = 0; k0 < Nn; k0 += 32) {
    {
      const float* ap = adjb + (size_t)(m0 + ar) * Nn + k0 + ac * 8;
      float4 v0 = *(const float4*)ap;
      float4 v1 = *(const float4*)(ap + 4);
      uint4 pk = make_uint4(pack2bf(v0.x, v0.y), pack2bf(v0.z, v0.w),
                            pack2bf(v1.x, v1.y), pack2bf(v1.z, v1.w));
      *(uint4*)&As[ar * LSTR + ac * 8] = pk;
    }
#pragma unroll
    for (int q = 0; q < 2; ++q) {
      int s = tid + 512 * q;
      int r = s >> 2, cg = s & 3;         // h-row 0..255
      *(uint4*)&Bs[r * LSTR + cg * 8] =
          *(const uint4*)(supb + (size_t)r * Nn + k0 + cg * 8);
    }
    __syncthreads();
    bf16x8 af[4], bfr[4];
#pragma unroll
    for (int i = 0; i < 4; ++i) {
      af[i]  = *(const bf16x8*)&As[(wr * 64 + i * 16 + (lane & 15)) * LSTR + (lane >> 4) * 8];
      bfr[i] = *(const bf16x8*)&Bs[(wc * 64 + i * 16 + (lane & 15)) * LSTR + (lane >> 4) * 8];
    }
#pragma unroll
    for (int mi = 0; mi < 4; ++mi)
#pragma unroll
      for (int nt = 0; nt < 4; ++nt)
        acc[mi][nt] = __builtin_amdgcn_mfma_f32_16x16x32_bf16(af[mi], bfr[nt], acc[mi][nt], 0, 0, 0);
    __syncthreads();
  }

  // Epilogue. red in As space: s1[128*4] | s2 at +512 | sc at +1024 (floats)
  float* red = (float*)As;
  float b0v[4], g0v[4], be0v[4];
#pragma unroll
  for (int nt = 0; nt < 4; ++nt) {
    int col = wc * 64 + nt * 16 + (lane & 15);
    b0v[nt] = b0[col]; g0v[nt] = g0[col]; be0v[nt] = be0[col];
  }
#pragma unroll
  for (int mi = 0; mi < 4; ++mi)
#pragma unroll
    for (int rg = 0; rg < 4; ++rg) {
      float s1 = 0.f, s2 = 0.f;
#pragma unroll
      for (int nt = 0; nt < 4; ++nt) {
        float x = acc[mi][nt][rg] + b0v[nt];
        s1 += x; s2 += x * x;
      }
#pragma unroll
      for (int off = 8; off >= 1; off >>= 1) {
        s1 += __shfl_xor(s1, off);
        s2 += __shfl_xor(s2, off);
      }
      if ((lane & 15) == 0) {
        int row = wr * 64 + mi * 16 + (lane >> 4) * 4 + rg;
        red[row * 4 + wc] = s1;
        red[512 + row * 4 + wc] = s2;
      }
    }
  __syncthreads();
#pragma unroll
  for (int mi = 0; mi < 4; ++mi)
#pragma unroll
    for (int rg = 0; rg < 4; ++rg) {
      int row = wr * 64 + mi * 16 + (lane >> 4) * 4 + rg;
      float s1 = red[row*4] + red[row*4+1] + red[row*4+2] + red[row*4+3];
      float s2 = red[512+row*4] + red[512+row*4+1] + red[512+row*4+2] + red[512+row*4+3];
      float m = s1 * (1.0f / Hn);
      float var = s2 * (1.0f / Hn) - m * m;
      float rstd = 1.0f / sqrtf(var + EPS);
      float sc = 0.f;
#pragma unroll
      for (int nt = 0; nt < 4; ++nt) {
        float x = acc[mi][nt][rg] + b0v[nt];
        float zz = (x - m) * rstd * g0v[nt] + be0v[nt];
        sc += fmaxf(zz, 0.f);
      }
#pragma unroll
      for (int off = 8; off >= 1; off >>= 1) sc += __shfl_xor(sc, off);
      if ((lane & 15) == 0) red[1024 + row * 4 + wc] = sc;
    }
  __syncthreads();
  if (tid < 128) {
    float s = red[1024+tid*4] + red[1024+tid*4+1] + red[1024+tid*4+2] + red[1024+tid*4+3];
    scores[b * Nn + m0 + tid] = s;
  }
}

// ---------------------------------------------------------------------------
// k3b: grid (256 batches x 4 n-chunks). Top-4 selection per stage (redundant
// across chunks, deterministic), then fp64 partials of t_c = adj_row_c@feat[b]
// over this chunk. feat read exactly once.
// ---------------------------------------------------------------------------
__global__ __launch_bounds__(256) void k3b_part(
    const float* __restrict__ adj, const float* __restrict__ feat,
    const float* __restrict__ scores, const int* __restrict__ sid,
    int* __restrict__ candbuf, double* __restrict__ px)
{
  __shared__ float sc_s[Nn];
  __shared__ int sid_s[Nn];
  __shared__ __align__(16) float adjs[20][128];
  __shared__ unsigned long long redk[4];
  __shared__ int cand[20], candv[20];
  const int tid = (int)threadIdx.x;
  const int b = blockIdx.x >> 2, ch = blockIdx.x & 3;

  for (int i = tid; i < Nn; i += 256) {
    sc_s[i] = scores[b * Nn + i];
    sid_s[i] = sid[b * Nn + i];
  }
  __syncthreads();

  for (int s = 0; s < NSn; ++s)
    for (int j = 0; j < 4; ++j) {
      unsigned long long best = 0ull;
      for (int i = tid; i < Nn; i += 256)
        if (sid_s[i] == s) {
          unsigned int fb = __float_as_uint(sc_s[i]);
          fb = (fb & 0x80000000u) ? ~fb : (fb | 0x80000000u);
          unsigned long long key = ((unsigned long long)fb << 32) |
                                   (unsigned long long)(unsigned)(Nn - 1 - i);
          if (key > best) best = key;
        }
#pragma unroll
      for (int off = 32; off >= 1; off >>= 1) {
        unsigned long long o = __shfl_xor(best, off);
        if (o > best) best = o;
      }
      if ((tid & 63) == 0) redk[tid >> 6] = best;
      __syncthreads();
      if (tid == 0) {
        unsigned long long bb = redk[0];
        if (redk[1] > bb) bb = redk[1];
        if (redk[2] > bb) bb = redk[2];
        if (redk[3] > bb) bb = redk[3];
        int c = s * 4 + j;
        if (bb != 0ull) {
          int node = Nn - 1 - (int)(bb & 0xFFFFFFFFull);
          cand[c] = node; candv[c] = 1; sid_s[node] = -1;
        } else {
          cand[c] = 0; candv[c] = 0;
        }
      }
      __syncthreads();
    }

  if (ch == 0 && tid < 20) {
    candbuf[b * 40 + tid] = cand[tid];
    candbuf[b * 40 + 20 + tid] = candv[tid];
  }

  const float* adjb = adj + ((size_t)b << 18);
  for (int idx = tid; idx < 20 * 128; idx += 256) {
    int c = idx >> 7, n = idx & 127;
    adjs[c][n] = adjb[((size_t)cand[c] << 9) + ch * 128 + n];
  }
  __syncthreads();

  double t[20];
#pragma unroll
  for (int c = 0; c < 20; ++c) t[c] = 0.0;
  const float* fp = feat + ((size_t)b << 17) + (((size_t)ch * 128) << 8) + tid;
  for (int n0 = 0; n0 < 128; n0 += 4) {
    double d0 = (double)fp[(size_t)(n0 + 0) << 8];
    double d1 = (double)fp[(size_t)(n0 + 1) << 8];
    double d2 = (double)fp[(size_t)(n0 + 2) << 8];
    double d3 = (double)fp[(size_t)(n0 + 3) << 8];
#pragma unroll
    for (int c = 0; c < 20; ++c) {
      float4 av = *(const float4*)&adjs[c][n0];
      t[c] += (double)av.x * d0 + (double)av.y * d1 +
              (double)av.z * d2 + (double)av.w * d3;
    }
  }
  double* pxb = px + ((size_t)(b * 4 + ch) * 20) * 256 + tid;
#pragma unroll
  for (int c = 0; c < 20; ++c) pxb[(size_t)c * 256] = t[c];
}

// ---------------------------------------------------------------------------
__device__ __forceinline__ float brs(float v) {
  __shared__ float sb[4];
#pragma unroll
  for (int off = 32; off >= 1; off >>= 1) v += __shfl_xor(v, off);
  __syncthreads();
  if ((threadIdx.x & 63) == 0) sb[threadIdx.x >> 6] = v;
  __syncthreads();
  return sb[0] + sb[1] + sb[2] + sb[3];
}

// ---------------------------------------------------------------------------
// k3c: one block/batch. Reduce t partials, x = t @ W0 (fp32), exact LN0
// scores per candidate (per-wave parallel), winner per stage, then the tail.
// ---------------------------------------------------------------------------
__global__ __launch_bounds__(256) void k3c_final(
    const double* __restrict__ px, const int* __restrict__ candbuf,
    const float* __restrict__ W0, const float* __restrict__ b0,
    const float* __restrict__ b1, const float* __restrict__ W2,
    const float* __restrict__ b2, const float* __restrict__ g0,
    const float* __restrict__ be0, const float* __restrict__ g1,
    const float* __restrict__ be1, const float* __restrict__ g2,
    const float* __restrict__ be2, const float* __restrict__ fcW,
    const float* __restrict__ fcb, float* __restrict__ out)
{
  __shared__ __align__(16) float tfT[Fn * 20];   // [f][c]
  __shared__ float xb[20][Hn];
  __shared__ float b0s[Hn], g0s[Hn], be0s[Hn];
  __shared__ float cm[20], cr[20], csc[20];
  __shared__ int candL[20], candvL[20], winslot[NSn];
  __shared__ float xs[Hn];
  const int tid = (int)threadIdx.x;
  const int b = blockIdx.x;

  if (tid < 20) {
    candL[tid] = candbuf[b * 40 + tid];
    candvL[tid] = candbuf[b * 40 + 20 + tid];
  }
  b0s[tid] = b0[tid]; g0s[tid] = g0[tid]; be0s[tid] = be0[tid];
  {
    const double* pxb = px + ((size_t)b * 4 * 20) * 256 + tid;
#pragma unroll
    for (int c = 0; c < 20; ++c) {
      double t = pxb[(size_t)c * 256] + pxb[(size_t)(20 + c) * 256] +
                 pxb[(size_t)(40 + c) * 256] + pxb[(size_t)(60 + c) * 256];
      tfT[tid * 20 + c] = (float)t;
    }
  }
  __syncthreads();

  {
    float xc[20];
#pragma unroll
    for (int c = 0; c < 20; ++c) xc[c] = 0.f;
    for (int f = 0; f < Fn; ++f) {
      float w = W0[(size_t)f * Hn + tid];
      const float* tp = &tfT[f * 20];
      float4 t0 = *(const float4*)(tp);
      float4 t1 = *(const float4*)(tp + 4);
      float4 t2 = *(const float4*)(tp + 8);
      float4 t3 = *(const float4*)(tp + 12);
      float4 t4 = *(const float4*)(tp + 16);
      xc[0] = fmaf(t0.x, w, xc[0]);   xc[1] = fmaf(t0.y, w, xc[1]);
      xc[2] = fmaf(t0.z, w, xc[2]);   xc[3] = fmaf(t0.w, w, xc[3]);
      xc[4] = fmaf(t1.x, w, xc[4]);   xc[5] = fmaf(t1.y, w, xc[5]);
      xc[6] = fmaf(t1.z, w, xc[6]);   xc[7] = fmaf(t1.w, w, xc[7]);
      xc[8] = fmaf(t2.x, w, xc[8]);   xc[9] = fmaf(t2.y, w, xc[9]);
      xc[10] = fmaf(t2.z, w, xc[10]); xc[11] = fmaf(t2.w, w, xc[11]);
      xc[12] = fmaf(t3.x, w, xc[12]); xc[13] = fmaf(t3.y, w, xc[13]);
      xc[14] = fmaf(t3.z, w, xc[14]); xc[15] = fmaf(t3.w, w, xc[15]);
      xc[16] = fmaf(t4.x, w, xc[16]); xc[17] = fmaf(t4.y, w, xc[17]);
      xc[18] = fmaf(t4.z, w, xc[18]); xc[19] = fmaf(t4.w, w, xc[19]);
    }
#pragma unroll
    for (int c = 0; c < 20; ++c) xb[c][tid] = xc[c];
  }
  __syncthreads();

  {
    const int wv = tid >> 6, lane = tid & 63;
    for (int c = wv; c < 20; c += 4) {
      float v0 = xb[c][lane] + b0s[lane];
      float v1 = xb[c][lane + 64] + b0s[lane + 64];
      float v2 = xb[c][lane + 128] + b0s[lane + 128];
      float v3 = xb[c][lane + 192] + b0s[lane + 192];
      float s = v0 + v1 + v2 + v3;
#pragma unroll
      for (int off = 32; off >= 1; off >>= 1) s += __shfl_xor(s, off);
      float m = s * (1.0f / Hn);
      float d0 = v0 - m, d1 = v1 - m, d2 = v2 - m, d3 = v3 - m;
      float s2 = d0 * d0 + d1 * d1 + d2 * d2 + d3 * d3;
#pragma unroll
      for (int off = 32; off >= 1; off >>= 1) s2 += __shfl_xor(s2, off);
      float rstd = 1.0f / sqrtf(s2 * (1.0f / Hn) + EPS);
      float sc = fmaxf(d0 * rstd * g0s[lane] + be0s[lane], 0.f) +
                 fmaxf(d1 * rstd * g0s[lane + 64] + be0s[lane + 64], 0.f) +
                 fmaxf(d2 * rstd * g0s[lane + 128] + be0s[lane + 128], 0.f) +
                 fmaxf(d3 * rstd * g0s[lane + 192] + be0s[lane + 192], 0.f);
#pragma unroll
      for (int off = 32; off >= 1; off >>= 1) sc += __shfl_xor(sc, off);
      if (lane == 0) { cm[c] = m; cr[c] = rstd; csc[c] = sc; }
    }
  }
  __syncthreads();

  if (tid == 0) {
#pragma unroll
    for (int s = 0; s < NSn; ++s) {
      int wsl = s * 4;
      float bestv = 0.f; int bestn = 0; bool any = false;
      for (int j = 0; j < 4; ++j) {
        int c = s * 4 + j;
        if (!candvL[c]) continue;
        float v = csc[c]; int node = candL[c];
        if (!any || v > bestv || (v == bestv && node < bestn)) {
          any = true; bestv = v; bestn = node; wsl = c;
        }
      }
      winslot[s] = wsl;
    }
  }
  __syncthreads();

  const float b0t = b0s[tid], g0t = g0s[tid], be0t = be0s[tid];
  const float b1t = b1[tid], g1t = g1[tid], be1t = be1[tid];
  float xsum = 0.f;
  for (int s = 0; s < NSn; ++s) {
    int c = winslot[s];
    float xv = xb[c][tid] + b0t;
    float z0 = (xv - cm[c]) * cr[c] * g0t + be0t;
    float o = fmaxf(z0, 0.f) + b1t;
    float m1 = brs(o) * (1.0f / Hn);
    float d1 = o - m1;
    float v1 = brs(d1 * d1) * (1.0f / Hn);
    float z1 = d1 * (1.0f / sqrtf(v1 + EPS)) * g1t + be1t;
    xsum += fmaxf(z1, 0.f);
  }
  xs[tid] = xsum;
  __syncthreads();
  float y = 0.f;
  for (int h = 0; h < Hn; h += 4) {
    float4 xv4 = *(const float4*)&xs[h];
    y = fmaf(xv4.x, W2[(size_t)h * Hn + tid], y);
    y = fmaf(xv4.y, W2[(size_t)(h + 1) * Hn + tid], y);
    y = fmaf(xv4.z, W2[(size_t)(h + 2) * Hn + tid], y);
    y = fmaf(xv4.w, W2[(size_t)(h + 3) * Hn + tid], y);
  }
  y += b2[tid];
  float m2 = brs(y) * (1.0f / Hn);
  float d2 = y - m2;
  float v2 = brs(d2 * d2) * (1.0f / Hn);
  float z2 = d2 * (1.0f / sqrtf(v2 + EPS)) * g2[tid] + be2[tid];
  float p = fmaxf(z2, 0.f) * fcW[tid];
  float tot = brs(p);
  if (tid == 0) out[b] = tot + fcb[0];
}

// ---------------------------------------------------------------------------
extern "C" void kernel_launch(void* const* d_in, const int* in_sizes, int n_in,
                              void* d_out, int out_size, void* d_ws, size_t ws_size,
                              hipStream_t stream)
{
  (void)in_sizes; (void)n_in; (void)out_size; (void)ws_size;
  const float* adj  = (const float*)d_in[0];
  const float* feat = (const float*)d_in[1];
  const int*   sid  = (const int*)d_in[2];
  const float* W0   = (const float*)d_in[3];
  const float* b0   = (const float*)d_in[4];
  const float* b1   = (const float*)d_in[5];
  const float* W2   = (const float*)d_in[6];
  const float* b2   = (const float*)d_in[7];
  const float* g0   = (const float*)d_in[8];
  const float* be0  = (const float*)d_in[9];
  const float* g1   = (const float*)d_in[10];
  const float* be1  = (const float*)d_in[11];
  const float* g2   = (const float*)d_in[12];
  const float* be2  = (const float*)d_in[13];
  const float* fcW  = (const float*)d_in[14];
  const float* fcb  = (const float*)d_in[15];
  float* out = (float*)d_out;

  // ws: supT bf16 [B][H][N] 67,108,864 | W0T bf16 131,072 | scores f32 524,288
  //     | candbuf int 40,960 | px f64 41,943,040
  unsigned short* supT = (unsigned short*)d_ws;
  unsigned short* W0T  = (unsigned short*)((char*)d_ws + 67108864);
  float* scores        = (float*)((char*)d_ws + 67239936);
  int* candbuf         = (int*)((char*)d_ws + 67764224);
  double* px           = (double*)((char*)d_ws + 67805184);

  k0_prep<<<dim3(16), dim3(256), 0, stream>>>(W0, W0T);
  k1_support<<<dim3(1024), dim3(512), 0, stream>>>(feat, W0T, supT);
  k2_scores<<<dim3(1024), dim3(512), 0, stream>>>(adj, supT, b0, g0, be0, scores);
  k3b_part<<<dim3(1024), dim3(256), 0, stream>>>(adj, feat, scores, sid, candbuf, px);
  k3c_final<<<dim3(256), dim3(256), 0, stream>>>(px, candbuf,
      W0, b0, b1, W2, b2, g0, be0, g1, be1, g2, be2, fcW, fcb, out);
}

// Round 5
// 696.296 us; speedup vs baseline: 1.4041x; 1.0080x over previous
//
#include <hip/hip_runtime.h>
#include <stdint.h>

#define Bn 256
#define Nn 512
#define Fn 256
#define Hn 256
#define NSn 5
#define EPS 1e-5f
#define LSTR 56   // LDS row stride in ushorts (112B: 16B-aligned, 2-lane bank groups)

typedef __attribute__((ext_vector_type(8))) short bf16x8;
typedef __attribute__((ext_vector_type(4))) float f32x4;

__device__ __forceinline__ unsigned short f2bf(float x) {
  unsigned int u = __float_as_uint(x);
  u += 0x7FFFu + ((u >> 16) & 1u);          // RTNE
  return (unsigned short)(u >> 16);
}
// Packed f32x2 -> bf16x2. gfx950 has v_cvt_pk_bf16_f32 (1 instr); fall back
// to the proven manual RTNE if the builtin is absent. Rounding-mode deltas are
// selection-safe: selection is guarded by top-4 + exact fp64 re-check.
__device__ __forceinline__ unsigned int pack2bf(float a, float b) {
#if __has_builtin(__builtin_amdgcn_cvt_pk_bf16_f32)
  auto r = __builtin_amdgcn_cvt_pk_bf16_f32(a, b);
  unsigned int u;
  __builtin_memcpy(&u, &r, 4);
  return u;
#else
  return (unsigned int)f2bf(a) | ((unsigned int)f2bf(b) << 16);
#endif
}

// ---------------------------------------------------------------------------
// k0: W0T[h][f] = bf16(W0[f][h]) via LDS tile transpose (coalesced R/W).
// ---------------------------------------------------------------------------
__global__ __launch_bounds__(256) void k0_prep(const float* __restrict__ W0,
                                               unsigned short* __restrict__ W0T) {
  __shared__ float tile[64][68];
  const int tid = (int)threadIdx.x;
  const int ti = blockIdx.x >> 2, tj = blockIdx.x & 3;   // f-tile, h-tile
#pragma unroll
  for (int q = 0; q < 4; ++q) {
    int s = tid + 256 * q;
    int r = s >> 4, c4 = s & 15;
    *(float4*)&tile[r][c4 * 4] =
        *(const float4*)(W0 + (size_t)(ti * 64 + r) * Hn + tj * 64 + c4 * 4);
  }
  __syncthreads();
#pragma unroll
  for (int q = 0; q < 4; ++q) {
    int s = tid + 256 * q;
    int hh = s >> 4, fq = s & 15;
    int ff = fq * 4;
    float t0 = tile[ff + 0][hh], t1 = tile[ff + 1][hh];
    float t2 = tile[ff + 2][hh], t3 = tile[ff + 3][hh];
    *(uint2*)(W0T + (size_t)(tj * 64 + hh) * Fn + ti * 64 + ff) =
        make_uint2(pack2bf(t0, t1), pack2bf(t2, t3));
  }
}

// ---------------------------------------------------------------------------
// k1: supT[b][h][node] = bf16((features@W0)[node][h]) via MFMA bf16.
// 128x256 tile, 512 threads = 8 waves (2 row-halves x 4 col-quarters),
// wave tile 64x64 = acc[4][4] (proven mapping). K=256, BK=32.
// ---------------------------------------------------------------------------
__global__ __launch_bounds__(512) void k1_support(
    const float* __restrict__ feat, const unsigned short* __restrict__ W0T,
    unsigned short* __restrict__ supT)
{
  __shared__ __align__(16) unsigned short As[128 * LSTR];
  __shared__ __align__(16) unsigned short Bs[256 * LSTR];
  const int tid = (int)threadIdx.x;
  const int wv = tid >> 6, lane = tid & 63;
  const int wr = wv >> 2, wc = wv & 3;
  const int m0 = blockIdx.x * 128;
  f32x4 acc[4][4];
  const f32x4 z4 = {0.f, 0.f, 0.f, 0.f};
#pragma unroll
  for (int i = 0; i < 4; ++i)
#pragma unroll
    for (int j = 0; j < 4; ++j) acc[i][j] = z4;

  const int ar = tid >> 2, ac = tid & 3;   // A: row 0..127, col-group (8 elems)
  for (int k0 = 0; k0 < Fn; k0 += 32) {
    {
      const float* ap = feat + (size_t)(m0 + ar) * Fn + k0 + ac * 8;
      float4 v0 = *(const float4*)ap;
      float4 v1 = *(const float4*)(ap + 4);
      uint4 pk = make_uint4(pack2bf(v0.x, v0.y), pack2bf(v0.z, v0.w),
                            pack2bf(v1.x, v1.y), pack2bf(v1.z, v1.w));
      *(uint4*)&As[ar * LSTR + ac * 8] = pk;
    }
#pragma unroll
    for (int q = 0; q < 2; ++q) {
      int s = tid + 512 * q;              // 0..1023
      int r = s >> 2, cg = s & 3;         // h-row 0..255
      *(uint4*)&Bs[r * LSTR + cg * 8] =
          *(const uint4*)(W0T + (size_t)r * Fn + k0 + cg * 8);
    }
    __syncthreads();
    bf16x8 af[4], bfr[4];
#pragma unroll
    for (int i = 0; i < 4; ++i) {
      af[i]  = *(const bf16x8*)&As[(wr * 64 + i * 16 + (lane & 15)) * LSTR + (lane >> 4) * 8];
      bfr[i] = *(const bf16x8*)&Bs[(wc * 64 + i * 16 + (lane & 15)) * LSTR + (lane >> 4) * 8];
    }
#pragma unroll
    for (int mi = 0; mi < 4; ++mi)
#pragma unroll
      for (int nt = 0; nt < 4; ++nt)
        acc[mi][nt] = __builtin_amdgcn_mfma_f32_16x16x32_bf16(af[mi], bfr[nt], acc[mi][nt], 0, 0, 0);
    __syncthreads();
  }
  const int b = m0 >> 9;
  const int nodebase = (m0 & 511) + wr * 64;
  unsigned short* outb = supT + ((size_t)b << 17);
#pragma unroll
  for (int mi = 0; mi < 4; ++mi)
#pragma unroll
    for (int nt = 0; nt < 4; ++nt) {
      int h = wc * 64 + nt * 16 + (lane & 15);
      int node = nodebase + mi * 16 + (lane >> 4) * 4;
      *(uint2*)(outb + (size_t)h * Nn + node) =
          make_uint2(pack2bf(acc[mi][nt][0], acc[mi][nt][1]),
                     pack2bf(acc[mi][nt][2], acc[mi][nt][3]));
    }
}

// ---------------------------------------------------------------------------
// k2: per batch, scores[node] = sum_h relu(LN0(adj@sup + b0)) via MFMA bf16.
// 128x256 tile, 512 threads / 8 waves; fused LN epilogue; x never stored.
// b = id>>2 keeps the 4 blocks of a batch temporally adjacent (supT reuse).
// ---------------------------------------------------------------------------
__global__ __launch_bounds__(512) void k2_scores(
    const float* __restrict__ adj, const unsigned short* __restrict__ supT,
    const float* __restrict__ b0, const float* __restrict__ g0,
    const float* __restrict__ be0, float* __restrict__ scores)
{
  __shared__ __align__(16) unsigned short As[128 * LSTR];
  __shared__ __align__(16) unsigned short Bs[256 * LSTR];
  const int tid = (int)threadIdx.x;
  const int wv = tid >> 6, lane = tid & 63;
  const int wr = wv >> 2, wc = wv & 3;
  const int b = blockIdx.x >> 2;
  const int m0 = (blockIdx.x & 3) * 128;
  const float* adjb = adj + ((size_t)b << 18);
  const unsigned short* supb = supT + ((size_t)b << 17);
  f32x4 acc[4][4];
  const f32x4 z4 = {0.f, 0.f, 0.f, 0.f};
#pragma unroll
  for (int i = 0; i < 4; ++i)
#pragma unroll
    for (int j = 0; j < 4; ++j) acc[i][j] = z4;

  const int ar = tid >> 2, ac = tid & 3;
  for (int k0 = 0; k0 < Nn; k0 += 32) {
    {
      const float* ap = adjb + (size_t)(m0 + ar) * Nn + k0 + ac * 8;
      float4 v0 = *(const float4*)ap;
      float4 v1 = *(const float4*)(ap + 4);
      uint4 pk = make_uint4(pack2bf(v0.x, v0.y), pack2bf(v0.z, v0.w),
                            pack2bf(v1.x, v1.y), pack2bf(v1.z, v1.w));
      *(uint4*)&As[ar * LSTR + ac * 8] = pk;
    }
#pragma unroll
    for (int q = 0; q < 2; ++q) {
      int s = tid + 512 * q;
      int r = s >> 2, cg = s & 3;         // h-row 0..255
      *(uint4*)&Bs[r * LSTR + cg * 8] =
          *(const uint4*)(supb + (size_t)r * Nn + k0 + cg * 8);
    }
    __syncthreads();
    bf16x8 af[4], bfr[4];
#pragma unroll
    for (int i = 0; i < 4; ++i) {
      af[i]  = *(const bf16x8*)&As[(wr * 64 + i * 16 + (lane & 15)) * LSTR + (lane >> 4) * 8];
      bfr[i] = *(const bf16x8*)&Bs[(wc * 64 + i * 16 + (lane & 15)) * LSTR + (lane >> 4) * 8];
    }
#pragma unroll
    for (int mi = 0; mi < 4; ++mi)
#pragma unroll
      for (int nt = 0; nt < 4; ++nt)
        acc[mi][nt] = __builtin_amdgcn_mfma_f32_16x16x32_bf16(af[mi], bfr[nt], acc[mi][nt], 0, 0, 0);
    __syncthreads();
  }

  // Epilogue. red in As space: s1[128*4] | s2 at +512 | sc at +1024 (floats)
  float* red = (float*)As;
  float b0v[4], g0v[4], be0v[4];
#pragma unroll
  for (int nt = 0; nt < 4; ++nt) {
    int col = wc * 64 + nt * 16 + (lane & 15);
    b0v[nt] = b0[col]; g0v[nt] = g0[col]; be0v[nt] = be0[col];
  }
#pragma unroll
  for (int mi = 0; mi < 4; ++mi)
#pragma unroll
    for (int rg = 0; rg < 4; ++rg) {
      float s1 = 0.f, s2 = 0.f;
#pragma unroll
      for (int nt = 0; nt < 4; ++nt) {
        float x = acc[mi][nt][rg] + b0v[nt];
        s1 += x; s2 += x * x;
      }
#pragma unroll
      for (int off = 8; off >= 1; off >>= 1) {
        s1 += __shfl_xor(s1, off);
        s2 += __shfl_xor(s2, off);
      }
      if ((lane & 15) == 0) {
        int row = wr * 64 + mi * 16 + (lane >> 4) * 4 + rg;
        red[row * 4 + wc] = s1;
        red[512 + row * 4 + wc] = s2;
      }
    }
  __syncthreads();
#pragma unroll
  for (int mi = 0; mi < 4; ++mi)
#pragma unroll
    for (int rg = 0; rg < 4; ++rg) {
      int row = wr * 64 + mi * 16 + (lane >> 4) * 4 + rg;
      float s1 = red[row*4] + red[row*4+1] + red[row*4+2] + red[row*4+3];
      float s2 = red[512+row*4] + red[512+row*4+1] + red[512+row*4+2] + red[512+row*4+3];
      float m = s1 * (1.0f / Hn);
      float var = s2 * (1.0f / Hn) - m * m;
      float rstd = 1.0f / sqrtf(var + EPS);
      float sc = 0.f;
#pragma unroll
      for (int nt = 0; nt < 4; ++nt) {
        float x = acc[mi][nt][rg] + b0v[nt];
        float zz = (x - m) * rstd * g0v[nt] + be0v[nt];
        sc += fmaxf(zz, 0.f);
      }
#pragma unroll
      for (int off = 8; off >= 1; off >>= 1) sc += __shfl_xor(sc, off);
      if ((lane & 15) == 0) red[1024 + row * 4 + wc] = sc;
    }
  __syncthreads();
  if (tid < 128) {
    float s = red[1024+tid*4] + red[1024+tid*4+1] + red[1024+tid*4+2] + red[1024+tid*4+3];
    scores[b * Nn + m0 + tid] = s;
  }
}

// ---------------------------------------------------------------------------
// k3a: one block/batch. Top-4 per stage from bf16 scores (iterative block
// argmax, jnp tie rule = smallest index). Hoisted out of k3b so the selection
// runs once per batch instead of 4x.
// ---------------------------------------------------------------------------
__global__ __launch_bounds__(256) void k3a_select(
    const float* __restrict__ scores, const int* __restrict__ sid,
    int* __restrict__ candbuf)
{
  __shared__ float sc_s[Nn];
  __shared__ int sid_s[Nn];
  __shared__ unsigned long long redk[4];
  __shared__ int cand[20], candv[20];
  const int tid = (int)threadIdx.x;
  const int b = blockIdx.x;

  for (int i = tid; i < Nn; i += 256) {
    sc_s[i] = scores[b * Nn + i];
    sid_s[i] = sid[b * Nn + i];
  }
  __syncthreads();

  for (int s = 0; s < NSn; ++s)
    for (int j = 0; j < 4; ++j) {
      unsigned long long best = 0ull;
      for (int i = tid; i < Nn; i += 256)
        if (sid_s[i] == s) {
          unsigned int fb = __float_as_uint(sc_s[i]);
          fb = (fb & 0x80000000u) ? ~fb : (fb | 0x80000000u);
          unsigned long long key = ((unsigned long long)fb << 32) |
                                   (unsigned long long)(unsigned)(Nn - 1 - i);
          if (key > best) best = key;
        }
#pragma unroll
      for (int off = 32; off >= 1; off >>= 1) {
        unsigned long long o = __shfl_xor(best, off);
        if (o > best) best = o;
      }
      if ((tid & 63) == 0) redk[tid >> 6] = best;
      __syncthreads();
      if (tid == 0) {
        unsigned long long bb = redk[0];
        if (redk[1] > bb) bb = redk[1];
        if (redk[2] > bb) bb = redk[2];
        if (redk[3] > bb) bb = redk[3];
        int c = s * 4 + j;
        if (bb != 0ull) {
          int node = Nn - 1 - (int)(bb & 0xFFFFFFFFull);
          cand[c] = node; candv[c] = 1; sid_s[node] = -1;
        } else {
          cand[c] = 0; candv[c] = 0;
        }
      }
      __syncthreads();
    }

  if (tid < 20) {
    candbuf[b * 40 + tid] = cand[tid];
    candbuf[b * 40 + 20 + tid] = candv[tid];
  }
}

// ---------------------------------------------------------------------------
// k3b: grid (256 batches x 4 n-chunks). Pure compute now: stage the 20
// candidate adj-row slices, fp64 partials of t_c = adj_row_c @ feat[b] over
// this chunk. feat read exactly once across the grid.
// ---------------------------------------------------------------------------
__global__ __launch_bounds__(256) void k3b_part(
    const float* __restrict__ adj, const float* __restrict__ feat,
    const int* __restrict__ candbuf, double* __restrict__ px)
{
  __shared__ __align__(16) float adjs[20][128];
  __shared__ int cand[20];
  const int tid = (int)threadIdx.x;
  const int b = blockIdx.x >> 2, ch = blockIdx.x & 3;

  if (tid < 20) cand[tid] = candbuf[b * 40 + tid];
  __syncthreads();

  const float* adjb = adj + ((size_t)b << 18);
  for (int idx = tid; idx < 20 * 128; idx += 256) {
    int c = idx >> 7, n = idx & 127;
    adjs[c][n] = adjb[((size_t)cand[c] << 9) + ch * 128 + n];
  }
  __syncthreads();

  double t[20];
#pragma unroll
  for (int c = 0; c < 20; ++c) t[c] = 0.0;
  const float* fp = feat + ((size_t)b << 17) + (((size_t)ch * 128) << 8) + tid;
  for (int n0 = 0; n0 < 128; n0 += 4) {
    double d0 = (double)fp[(size_t)(n0 + 0) << 8];
    double d1 = (double)fp[(size_t)(n0 + 1) << 8];
    double d2 = (double)fp[(size_t)(n0 + 2) << 8];
    double d3 = (double)fp[(size_t)(n0 + 3) << 8];
#pragma unroll
    for (int c = 0; c < 20; ++c) {
      float4 av = *(const float4*)&adjs[c][n0];
      t[c] += (double)av.x * d0 + (double)av.y * d1 +
              (double)av.z * d2 + (double)av.w * d3;
    }
  }
  double* pxb = px + ((size_t)(b * 4 + ch) * 20) * 256 + tid;
#pragma unroll
  for (int c = 0; c < 20; ++c) pxb[(size_t)c * 256] = t[c];
}

// ---------------------------------------------------------------------------
__device__ __forceinline__ float brs(float v) {
  __shared__ float sb[4];
#pragma unroll
  for (int off = 32; off >= 1; off >>= 1) v += __shfl_xor(v, off);
  __syncthreads();
  if ((threadIdx.x & 63) == 0) sb[threadIdx.x >> 6] = v;
  __syncthreads();
  return sb[0] + sb[1] + sb[2] + sb[3];
}

// ---------------------------------------------------------------------------
// k3c: one block/batch. Reduce t partials, x = t @ W0 (fp32), exact LN0
// scores per candidate (per-wave parallel), winner per stage, then the tail.
// ---------------------------------------------------------------------------
__global__ __launch_bounds__(256) void k3c_final(
    const double* __restrict__ px, const int* __restrict__ candbuf,
    const float* __restrict__ W0, const float* __restrict__ b0,
    const float* __restrict__ b1, const float* __restrict__ W2,
    const float* __restrict__ b2, const float* __restrict__ g0,
    const float* __restrict__ be0, const float* __restrict__ g1,
    const float* __restrict__ be1, const float* __restrict__ g2,
    const float* __restrict__ be2, const float* __restrict__ fcW,
    const float* __restrict__ fcb, float* __restrict__ out)
{
  __shared__ __align__(16) float tfT[Fn * 20];   // [f][c]
  __shared__ float xb[20][Hn];
  __shared__ float b0s[Hn], g0s[Hn], be0s[Hn];
  __shared__ float cm[20], cr[20], csc[20];
  __shared__ int candL[20], candvL[20], winslot[NSn];
  __shared__ float xs[Hn];
  const int tid = (int)threadIdx.x;
  const int b = blockIdx.x;

  if (tid < 20) {
    candL[tid] = candbuf[b * 40 + tid];
    candvL[tid] = candbuf[b * 40 + 20 + tid];
  }
  b0s[tid] = b0[tid]; g0s[tid] = g0[tid]; be0s[tid] = be0[tid];
  {
    const double* pxb = px + ((size_t)b * 4 * 20) * 256 + tid;
#pragma unroll
    for (int c = 0; c < 20; ++c) {
      double t = pxb[(size_t)c * 256] + pxb[(size_t)(20 + c) * 256] +
                 pxb[(size_t)(40 + c) * 256] + pxb[(size_t)(60 + c) * 256];
      tfT[tid * 20 + c] = (float)t;
    }
  }
  __syncthreads();

  {
    float xc[20];
#pragma unroll
    for (int c = 0; c < 20; ++c) xc[c] = 0.f;
    for (int f = 0; f < Fn; ++f) {
      float w = W0[(size_t)f * Hn + tid];
      const float* tp = &tfT[f * 20];
      float4 t0 = *(const float4*)(tp);
      float4 t1 = *(const float4*)(tp + 4);
      float4 t2 = *(const float4*)(tp + 8);
      float4 t3 = *(const float4*)(tp + 12);
      float4 t4 = *(const float4*)(tp + 16);
      xc[0] = fmaf(t0.x, w, xc[0]);   xc[1] = fmaf(t0.y, w, xc[1]);
      xc[2] = fmaf(t0.z, w, xc[2]);   xc[3] = fmaf(t0.w, w, xc[3]);
      xc[4] = fmaf(t1.x, w, xc[4]);   xc[5] = fmaf(t1.y, w, xc[5]);
      xc[6] = fmaf(t1.z, w, xc[6]);   xc[7] = fmaf(t1.w, w, xc[7]);
      xc[8] = fmaf(t2.x, w, xc[8]);   xc[9] = fmaf(t2.y, w, xc[9]);
      xc[10] = fmaf(t2.z, w, xc[10]); xc[11] = fmaf(t2.w, w, xc[11]);
      xc[12] = fmaf(t3.x, w, xc[12]); xc[13] = fmaf(t3.y, w, xc[13]);
      xc[14] = fmaf(t3.z, w, xc[14]); xc[15] = fmaf(t3.w, w, xc[15]);
      xc[16] = fmaf(t4.x, w, xc[16]); xc[17] = fmaf(t4.y, w, xc[17]);
      xc[18] = fmaf(t4.z, w, xc[18]); xc[19] = fmaf(t4.w, w, xc[19]);
    }
#pragma unroll
    for (int c = 0; c < 20; ++c) xb[c][tid] = xc[c];
  }
  __syncthreads();

  {
    const int wv = tid >> 6, lane = tid & 63;
    for (int c = wv; c < 20; c += 4) {
      float v0 = xb[c][lane] + b0s[lane];
      float v1 = xb[c][lane + 64] + b0s[lane + 64];
      float v2 = xb[c][lane + 128] + b0s[lane + 128];
      float v3 = xb[c][lane + 192] + b0s[lane + 192];
      float s = v0 + v1 + v2 + v3;
#pragma unroll
      for (int off = 32; off >= 1; off >>= 1) s += __shfl_xor(s, off);
      float m = s * (1.0f / Hn);
      float d0 = v0 - m, d1 = v1 - m, d2 = v2 - m, d3 = v3 - m;
      float s2 = d0 * d0 + d1 * d1 + d2 * d2 + d3 * d3;
#pragma unroll
      for (int off = 32; off >= 1; off >>= 1) s2 += __shfl_xor(s2, off);
      float rstd = 1.0f / sqrtf(s2 * (1.0f / Hn) + EPS);
      float sc = fmaxf(d0 * rstd * g0s[lane] + be0s[lane], 0.f) +
                 fmaxf(d1 * rstd * g0s[lane + 64] + be0s[lane + 64], 0.f) +
                 fmaxf(d2 * rstd * g0s[lane + 128] + be0s[lane + 128], 0.f) +
                 fmaxf(d3 * rstd * g0s[lane + 192] + be0s[lane + 192], 0.f);
#pragma unroll
      for (int off = 32; off >= 1; off >>= 1) sc += __shfl_xor(sc, off);
      if (lane == 0) { cm[c] = m; cr[c] = rstd; csc[c] = sc; }
    }
  }
  __syncthreads();

  if (tid == 0) {
#pragma unroll
    for (int s = 0; s < NSn; ++s) {
      int wsl = s * 4;
      float bestv = 0.f; int bestn = 0; bool any = false;
      for (int j = 0; j < 4; ++j) {
        int c = s * 4 + j;
        if (!candvL[c]) continue;
        float v = csc[c]; int node = candL[c];
        if (!any || v > bestv || (v == bestv && node < bestn)) {
          any = true; bestv = v; bestn = node; wsl = c;
        }
      }
      winslot[s] = wsl;
    }
  }
  __syncthreads();

  const float b0t = b0s[tid], g0t = g0s[tid], be0t = be0s[tid];
  const float b1t = b1[tid], g1t = g1[tid], be1t = be1[tid];
  float xsum = 0.f;
  for (int s = 0; s < NSn; ++s) {
    int c = winslot[s];
    float xv = xb[c][tid] + b0t;
    float z0 = (xv - cm[c]) * cr[c] * g0t + be0t;
    float o = fmaxf(z0, 0.f) + b1t;
    float m1 = brs(o) * (1.0f / Hn);
    float d1 = o - m1;
    float v1 = brs(d1 * d1) * (1.0f / Hn);
    float z1 = d1 * (1.0f / sqrtf(v1 + EPS)) * g1t + be1t;
    xsum += fmaxf(z1, 0.f);
  }
  xs[tid] = xsum;
  __syncthreads();
  float y = 0.f;
  for (int h = 0; h < Hn; h += 4) {
    float4 xv4 = *(const float4*)&xs[h];
    y = fmaf(xv4.x, W2[(size_t)h * Hn + tid], y);
    y = fmaf(xv4.y, W2[(size_t)(h + 1) * Hn + tid], y);
    y = fmaf(xv4.z, W2[(size_t)(h + 2) * Hn + tid], y);
    y = fmaf(xv4.w, W2[(size_t)(h + 3) * Hn + tid], y);
  }
  y += b2[tid];
  float m2 = brs(y) * (1.0f / Hn);
  float d2 = y - m2;
  float v2 = brs(d2 * d2) * (1.0f / Hn);
  float z2 = d2 * (1.0f / sqrtf(v2 + EPS)) * g2[tid] + be2[tid];
  float p = fmaxf(z2, 0.f) * fcW[tid];
  float tot = brs(p);
  if (tid == 0) out[b] = tot + fcb[0];
}

// ---------------------------------------------------------------------------
extern "C" void kernel_launch(void* const* d_in, const int* in_sizes, int n_in,
                              void* d_out, int out_size, void* d_ws, size_t ws_size,
                              hipStream_t stream)
{
  (void)in_sizes; (void)n_in; (void)out_size; (void)ws_size;
  const float* adj  = (const float*)d_in[0];
  const float* feat = (const float*)d_in[1];
  const int*   sid  = (const int*)d_in[2];
  const float* W0   = (const float*)d_in[3];
  const float* b0   = (const float*)d_in[4];
  const float* b1   = (const float*)d_in[5];
  const float* W2   = (const float*)d_in[6];
  const float* b2   = (const float*)d_in[7];
  const float* g0   = (const float*)d_in[8];
  const float* be0  = (const float*)d_in[9];
  const float* g1   = (const float*)d_in[10];
  const float* be1  = (const float*)d_in[11];
  const float* g2   = (const float*)d_in[12];
  const float* be2  = (const float*)d_in[13];
  const float* fcW  = (const float*)d_in[14];
  const float* fcb  = (const float*)d_in[15];
  float* out = (float*)d_out;

  // ws: supT bf16 [B][H][N] 67,108,864 | W0T bf16 131,072 | scores f32 524,288
  //     | candbuf int 40,960 | px f64 41,943,040
  unsigned short* supT = (unsigned short*)d_ws;
  unsigned short* W0T  = (unsigned short*)((char*)d_ws + 67108864);
  float* scores        = (float*)((char*)d_ws + 67239936);
  int* candbuf         = (int*)((char*)d_ws + 67764224);
  double* px           = (double*)((char*)d_ws + 67805184);

  k0_prep<<<dim3(16), dim3(256), 0, stream>>>(W0, W0T);
  k1_support<<<dim3(1024), dim3(512), 0, stream>>>(feat, W0T, supT);
  k2_scores<<<dim3(1024), dim3(512), 0, stream>>>(adj, supT, b0, g0, be0, scores);
  k3a_select<<<dim3(256), dim3(256), 0, stream>>>(scores, sid, candbuf);
  k3b_part<<<dim3(1024), dim3(256), 0, stream>>>(adj, feat, candbuf, px);
  k3c_final<<<dim3(256), dim3(256), 0, stream>>>(px, candbuf,
      W0, b0, b1, W2, b2, g0, be0, g1, be1, g2, be2, fcW, fcb, out);
}